// Round 11
// baseline (862.897 us; speedup 1.0000x reference)
//
#include <hip/hip_runtime.h>
#include <hip/hip_bf16.h>

constexpr int DIN = 16;
constexpr int D   = 256;
constexpr int NH  = 8;
constexpr int NC  = 32;
constexpr int MC  = 200;
constexpr int NT  = 8;
constexpr int BG  = 16;
constexpr int NL  = 6;
constexpr int PS  = 16;   // pool slices per graph
constexpr float NEG = 0.2f;

typedef __attribute__((ext_vector_type(8))) short bfrag;
typedef __attribute__((ext_vector_type(4))) float f32x4;

__device__ inline unsigned short f2bf(float f) {
    unsigned int u = __float_as_uint(f);
    u += 0x7FFFu + ((u >> 16) & 1u);
    return (unsigned short)(u >> 16);
}
__device__ inline float bf2f(unsigned short u) {
    return __uint_as_float((unsigned int)u << 16);
}

__device__ inline float dot_ilp(const float* g, const float* __restrict__ W, int K, int ldw, int t) {
    float a0 = 0.f, a1 = 0.f, a2 = 0.f, a3 = 0.f;
    for (int k = 0; k < K; k += 4) {
        a0 = fmaf(g[k + 0], W[(k + 0) * ldw + t], a0);
        a1 = fmaf(g[k + 1], W[(k + 1) * ldw + t], a1);
        a2 = fmaf(g[k + 2], W[(k + 2) * ldw + t], a2);
        a3 = fmaf(g[k + 3], W[(k + 3) * ldw + t], a3);
    }
    return (a0 + a1) + (a2 + a3);
}

// ---------------- device helpers ----------------

__device__ inline void enc_node(const float* x, const float* W, const float* b, const float* ls,
                                const float* lb, float* h, int n, int lane) {
    int c4 = lane * 4;
    float xs[DIN];
#pragma unroll
    for (int k = 0; k < DIN; k += 4) {
        float4 xv = *(const float4*)&x[n * DIN + k];
        xs[k] = xv.x; xs[k + 1] = xv.y; xs[k + 2] = xv.z; xs[k + 3] = xv.w;
    }
    float4 a = *(const float4*)&b[c4];
#pragma unroll
    for (int k = 0; k < DIN; k++) {
        float4 wv = *(const float4*)&W[k * D + c4];
        a.x = fmaf(xs[k], wv.x, a.x);
        a.y = fmaf(xs[k], wv.y, a.y);
        a.z = fmaf(xs[k], wv.z, a.z);
        a.w = fmaf(xs[k], wv.w, a.w);
    }
    float s = a.x + a.y + a.z + a.w;
#pragma unroll
    for (int msk = 1; msk <= 32; msk <<= 1) s += __shfl_xor(s, msk);
    float mu = s * (1.f / D);
    float4 dv = make_float4(a.x - mu, a.y - mu, a.z - mu, a.w - mu);
    float v2 = dv.x * dv.x + dv.y * dv.y + dv.z * dv.z + dv.w * dv.w;
#pragma unroll
    for (int msk = 1; msk <= 32; msk <<= 1) v2 += __shfl_xor(v2, msk);
    float rstd = rsqrtf(v2 * (1.f / D) + 1e-5f);
    float4 lsv = *(const float4*)&ls[c4];
    float4 lbv = *(const float4*)&lb[c4];
    float4 y = make_float4(fmaxf(dv.x * rstd * lsv.x + lbv.x, 0.f),
                           fmaxf(dv.y * rstd * lsv.y + lbv.y, 0.f),
                           fmaxf(dv.z * rstd * lsv.z + lbv.z, 0.f),
                           fmaxf(dv.w * rstd * lsv.w + lbv.w, 0.f));
    *(float4*)&h[(size_t)n * D + c4] = y;
}

// attn for one node (one full wave); depth-4 software pipeline.
// No running-max: logits bounded << exp overflow (order-free sums).
__device__ inline float4 attn_compute(const unsigned short* xl, const unsigned short* xr,
                                      const int* row_ptr, const int* col, const float* att,
                                      const float* gb, const float* gls, const float* glb,
                                      const float* h, int layer, int n, int lane) {
    int c4 = lane * 4;
    ushort4 xr4 = *(const ushort4*)&xr[(size_t)n * D + c4];
    float4 xrv = make_float4(bf2f(xr4.x), bf2f(xr4.y), bf2f(xr4.z), bf2f(xr4.w));
    float4 av  = *(const float4*)&att[c4];
    int beg = row_ptr[n], end = row_ptr[n + 1];
    int deg = end - beg;
    int myc = col[beg + min(lane, deg - 1)];
    float l = 0.f;
    float4 acc = make_float4(0.f, 0.f, 0.f, 0.f);
    auto loadx = [&](int i) -> ushort4 {
        if (i < deg) {
            int s = (i < 64) ? __shfl(myc, i) : col[beg + i];
            return *(const ushort4*)&xl[(size_t)s * D + c4];
        }
        return make_ushort4(0, 0, 0, 0);
    };
    auto step = [&](ushort4 x4) {
        float4 xlv = make_float4(bf2f(x4.x), bf2f(x4.y), bf2f(x4.z), bf2f(x4.w));
        float sx = xlv.x + xrv.x; sx = sx > 0.f ? sx : NEG * sx;
        float sy = xlv.y + xrv.y; sy = sy > 0.f ? sy : NEG * sy;
        float sz = xlv.z + xrv.z; sz = sz > 0.f ? sz : NEG * sz;
        float sw = xlv.w + xrv.w; sw = sw > 0.f ? sw : NEG * sw;
        float z = av.x * sx + av.y * sy + av.z * sz + av.w * sw;
        z += __shfl_xor(z, 1); z += __shfl_xor(z, 2); z += __shfl_xor(z, 4);
        float p = __expf(z);
        l += p;
        acc.x = fmaf(p, xlv.x, acc.x);
        acc.y = fmaf(p, xlv.y, acc.y);
        acc.z = fmaf(p, xlv.z, acc.z);
        acc.w = fmaf(p, xlv.w, acc.w);
    };
    ushort4 b0 = loadx(0), b1 = loadx(1), b2 = loadx(2), b3 = loadx(3);
    int e = 0;
    for (; e + 4 <= deg; e += 4) {
        ushort4 n0 = loadx(e + 4), n1 = loadx(e + 5), n2 = loadx(e + 6), n3 = loadx(e + 7);
        step(b0); step(b1); step(b2); step(b3);
        b0 = n0; b1 = n1; b2 = n2; b3 = n3;
    }
    if (e + 0 < deg) step(b0);
    if (e + 1 < deg) step(b1);
    if (e + 2 < deg) step(b2);
    float4 gbv = *(const float4*)&gb[c4];
    float rl = 1.f / l;
    float4 o = make_float4(acc.x * rl + gbv.x, acc.y * rl + gbv.y,
                           acc.z * rl + gbv.z, acc.w * rl + gbv.w);
    float s = o.x + o.y + o.z + o.w;
#pragma unroll
    for (int msk = 1; msk <= 32; msk <<= 1) s += __shfl_xor(s, msk);
    float mu = s * (1.f / D);
    float4 dv = make_float4(o.x - mu, o.y - mu, o.z - mu, o.w - mu);
    float v2 = dv.x * dv.x + dv.y * dv.y + dv.z * dv.z + dv.w * dv.w;
#pragma unroll
    for (int msk = 1; msk <= 32; msk <<= 1) v2 += __shfl_xor(v2, msk);
    float rstd = rsqrtf(v2 * (1.f / D) + 1e-5f);
    float4 glsv = *(const float4*)&gls[c4];
    float4 glbv = *(const float4*)&glb[c4];
    float y0 = dv.x * rstd * glsv.x + glbv.x;
    float y1 = dv.y * rstd * glsv.y + glbv.y;
    float y2 = dv.z * rstd * glsv.z + glbv.z;
    float y3 = dv.w * rstd * glsv.w + glbv.w;
    y0 = y0 > 0.f ? y0 : expm1f(y0);
    y1 = y1 > 0.f ? y1 : expm1f(y1);
    y2 = y2 > 0.f ? y2 : expm1f(y2);
    y3 = y3 > 0.f ? y3 : expm1f(y3);
    float4 prev = make_float4(0.f, 0.f, 0.f, 0.f);
    if (layer > 0) prev = *(const float4*)&h[(size_t)n * D + c4];
    return make_float4(prev.x + y0, prev.y + y1, prev.z + y2, prev.w + y3);
}

// MFMA GEMM on a 16-row tile, one wave handles one 16-col tile (ctg).
__device__ inline void gemm_one_ct(const unsigned short (*As)[264],
                                   const unsigned short* WpL, const unsigned short* WpR,
                                   const float* bl, const float* br,
                                   unsigned short* xl, unsigned short* xr,
                                   int N, int nb, int ctg, int lane) {
    int m = lane & 15, q = lane >> 4;
    float bLv = bl[ctg * 16 + m];
    float bRv = br[ctg * 16 + m];
    f32x4 accL = (f32x4){bLv, bLv, bLv, bLv};
    f32x4 accR = (f32x4){bRv, bRv, bRv, bRv};
#pragma unroll
    for (int ks = 0; ks < 8; ks++) {
        bfrag af = *(const bfrag*)&As[m][ks * 32 + q * 8];
        size_t off = (((size_t)ctg * 8 + ks) * 64 + lane) * 8;
        bfrag bL = *(const bfrag*)&WpL[off];
        bfrag bR = *(const bfrag*)&WpR[off];
        accL = __builtin_amdgcn_mfma_f32_16x16x32_bf16(af, bL, accL, 0, 0, 0);
        accR = __builtin_amdgcn_mfma_f32_16x16x32_bf16(af, bR, accR, 0, 0, 0);
    }
    int colg = ctg * 16 + m;
#pragma unroll
    for (int reg = 0; reg < 4; reg++) {
        int row = nb + q * 4 + reg;
        if (row < N) {
            xl[(size_t)row * D + colg] = f2bf(accL[reg]);
            xr[(size_t)row * D + colg] = f2bf(accR[reg]);
        }
    }
}

// 4-wave variant (wave w owns col-tiles w*4..w*4+3)
__device__ inline void gemm_core(const unsigned short (*As)[264],
                                 const unsigned short* WpL, const unsigned short* WpR,
                                 const float* bl, const float* br,
                                 unsigned short* xl, unsigned short* xr, int N, int nb, int T) {
    int lane = T & 63, w = T >> 6;
#pragma unroll
    for (int ct = 0; ct < 4; ct++)
        gemm_one_ct(As, WpL, WpR, bl, br, xl, xr, N, nb, w * 4 + ct, lane);
}

__device__ inline void repack_attn_one(const float* Wl, const float* Wr, unsigned short* Wp, int tid) {
    int lane = tid & 63;
    int r1 = tid >> 6;
    int ks = r1 & 7;
    int r2 = r1 >> 3;
    int ct = r2 & 15;
    int mi = r2 >> 4;
    int layer = mi >> 1, mat = mi & 1;
    const float* W = (mat == 0 ? Wl : Wr) + (size_t)layer * D * D;
    int n = ct * 16 + (lane & 15);
    int kb = ks * 32 + (lane >> 4) * 8;
    size_t base = (((size_t)(mi * 16 + ct) * 8 + ks) * 64 + lane) * 8;
#pragma unroll
    for (int j = 0; j < 8; j++) Wp[base + j] = f2bf(W[(size_t)(kb + j) * D + n]);
}

__device__ inline void repack_gen_one(const float* W, unsigned short* Wp, int K, int NCOL, int nks, int tid) {
    int lane = tid & 63;
    int r = tid >> 6;
    int ks = r % nks;
    int ct = r / nks;
    int n = ct * 16 + (lane & 15);
    int kb = ks * 32 + (lane >> 4) * 8;
    size_t base = (((size_t)ct * nks + ks) * 64 + lane) * 8;
#pragma unroll
    for (int j = 0; j < 8; j++) {
        int k = kb + j;
        Wp[base + j] = (n < NCOL && k < K) ? f2bf(W[(size_t)k * NCOL + n]) : (unsigned short)0;
    }
}

// ---------------- kernels (MEASUREMENT ROUND: idempotent bodies run 2x) ----------------

// encoder + repacks DOUBLED (idempotent); edge count atomics once.
__global__ __launch_bounds__(256) void fused_init_k(const float* __restrict__ x, const float* __restrict__ encW,
                                                    const float* __restrict__ encb, const float* __restrict__ encls,
                                                    const float* __restrict__ enclb, float* __restrict__ h, int N,
                                                    const int* __restrict__ dst, int* __restrict__ deg, int E,
                                                    const float* __restrict__ Wl, const float* __restrict__ Wr,
                                                    unsigned short* __restrict__ Wp,
                                                    const float* __restrict__ cW1, unsigned short* __restrict__ cW1p,
                                                    const float* __restrict__ cW2, unsigned short* __restrict__ cW2p,
                                                    const float* __restrict__ cW3, unsigned short* __restrict__ cW3p) {
    int gid = blockIdx.x * 256 + threadIdx.x;
    int lane = threadIdx.x & 63;
    int n = blockIdx.x * 4 + (threadIdx.x >> 6);
#pragma unroll 1
    for (int rep = 0; rep < 2; rep++) {
        asm volatile("" ::: "memory");
        if (n < N) enc_node(x, encW, encb, encls, enclb, h, n, lane);
        if (gid < NL * 2 * 16 * 8 * 64) repack_attn_one(Wl, Wr, Wp, gid);
        if (gid < 16 * 8 * 64) repack_gen_one(cW1, cW1p, D, D, 8, gid);
        if (gid < 8 * 8 * 64)  repack_gen_one(cW2, cW2p, D, 128, 8, gid);
        if (gid < 13 * 4 * 64) repack_gen_one(cW3, cW3p, 128, MC, 4, gid);
    }
    if (gid < E) atomicAdd(&deg[dst[gid]], 1);
}

// single-block scan DOUBLED (idempotent). Trailing sync prevents rep1's sd write
// racing rep0's post-scan reads.
__global__ __launch_bounds__(1024) void scan_k(const int* __restrict__ deg, int* __restrict__ row_ptr,
                                               int* __restrict__ fill, int N) {
    __shared__ int sd[1024];
    int t = threadIdx.x;
    int chunk = (N + 1023) >> 10;
    int lo = t * chunk, hi = min(lo + chunk, N);
#pragma unroll 1
    for (int rep = 0; rep < 2; rep++) {
        asm volatile("" ::: "memory");
        int s = 0;
        for (int i = lo; i < hi; i++) s += deg[i] + 1;
        sd[t] = s;
        __syncthreads();
        for (int off = 1; off < 1024; off <<= 1) {
            int v = (t >= off) ? sd[t - off] : 0;
            __syncthreads();
            sd[t] += v;
            __syncthreads();
        }
        int run = (t > 0) ? sd[t - 1] : 0;
        for (int i = lo; i < hi; i++) {
            row_ptr[i] = run; fill[i] = run;
            run += deg[i] + 1;
        }
        if (t == 1023) row_ptr[N] = sd[1023];
        __syncthreads();
    }
}

// scatter + layer-0 GEMM: GEMM half DOUBLED, scatter (atomics) once.
__global__ __launch_bounds__(256) void scatter_gemm0_k(const int* __restrict__ src, const int* __restrict__ dst,
                                                       int* __restrict__ fill, int* __restrict__ col, int E, int N,
                                                       const float* __restrict__ h,
                                                       const unsigned short* __restrict__ WpL,
                                                       const unsigned short* __restrict__ WpR,
                                                       const float* __restrict__ bl, const float* __restrict__ br,
                                                       unsigned short* __restrict__ xl, unsigned short* __restrict__ xr) {
    __shared__ unsigned short As[16][264];
    int T = threadIdx.x;
    int tt = blockIdx.x;
    int ntiles = (N + 15) >> 4;
    if (tt < ntiles) {
        int nb = tt * 16;
#pragma unroll 1
        for (int rep = 0; rep < 2; rep++) {
            asm volatile("" ::: "memory");
#pragma unroll
            for (int r = 0; r < 16; r++) {
                int row = nb + r;
                float v = (row < N) ? h[(size_t)row * D + T] : 0.f;
                As[r][T] = f2bf(v);
            }
            __syncthreads();
            gemm_core(As, WpL, WpR, bl, br, xl, xr, N, nb, T);
            __syncthreads();
        }
    }
    for (int e = blockIdx.x * 256 + T; e < E + N; e += gridDim.x * 256) {
        if (e < E) {
            int p = atomicAdd(&fill[dst[e]], 1);
            col[p] = src[e];
        } else {
            int n = e - E;
            int p = atomicAdd(&fill[n], 1);
            col[p] = n;
        }
    }
}

// row sort DOUBLED (sorting sorted data is idempotent).
__global__ __launch_bounds__(256) void sortcol_k(const int* __restrict__ row_ptr,
                                                 int* __restrict__ col, int N) {
    int lane = threadIdx.x & 63;
    int n = blockIdx.x * 4 + (threadIdx.x >> 6);
    if (n >= N) return;
    int beg = row_ptr[n], deg = row_ptr[n + 1] - beg;
    if (deg > 64) return;
#pragma unroll 1
    for (int rep = 0; rep < 2; rep++) {
        asm volatile("" ::: "memory");
        int key = (lane < deg) ? col[beg + lane] : 0x7FFFFFFF;
#pragma unroll
        for (int k = 2; k <= 64; k <<= 1) {
#pragma unroll
            for (int j = k >> 1; j > 0; j >>= 1) {
                int other = __shfl_xor(key, j);
                bool up = ((lane & k) == 0);
                bool takeMin = (((lane & j) == 0) == up);
                key = takeMin ? min(key, other) : max(key, other);
            }
        }
        if (lane < deg) col[beg + lane] = key;
    }
}

// attention: SINGLE rep (cost already known from round 9: 26.5 us/layer).
__global__ __launch_bounds__(256, 4) void attn_k(const unsigned short* __restrict__ xl_in,
                                                 const unsigned short* __restrict__ xr_in,
                                                 const int* __restrict__ row_ptr, const int* __restrict__ col,
                                                 const float* __restrict__ att, const float* __restrict__ gb,
                                                 const float* __restrict__ gls, const float* __restrict__ glb,
                                                 float* __restrict__ h, int layer, int N) {
    int T = threadIdx.x;
    int lane = T & 63, wv = T >> 6;
    int n = blockIdx.x * 4 + wv;
    if (n >= N) return;
    float4 res = attn_compute(xl_in, xr_in, row_ptr, col, att, gb, gls, glb, h, layer, n, lane);
    *(float4*)&h[(size_t)n * D + lane * 4] = res;
}

// GEMM-only kernel DOUBLED.
__global__ __launch_bounds__(256, 4) void gemm_lr_k(const float* __restrict__ h,
                                                    const unsigned short* __restrict__ WpL,
                                                    const unsigned short* __restrict__ WpR,
                                                    const float* __restrict__ bl, const float* __restrict__ br,
                                                    unsigned short* __restrict__ xl, unsigned short* __restrict__ xr,
                                                    int N) {
    __shared__ unsigned short As[16][264];
    int T = threadIdx.x;
    int nb = blockIdx.x * 16;
#pragma unroll 1
    for (int rep = 0; rep < 2; rep++) {
        asm volatile("" ::: "memory");
#pragma unroll
        for (int r = 0; r < 16; r++) {
            int row = nb + r;
            float v = (row < N) ? h[(size_t)row * D + T] : 0.f;
            As[r][T] = f2bf(v);
        }
        __syncthreads();
        gemm_core(As, WpL, WpR, bl, br, xl, xr, N, nb, T);
        __syncthreads();
    }
}

// color-head MLP DOUBLED.
__global__ __launch_bounds__(1024) void colorhead_k(const float* __restrict__ h, int N,
                                                    const unsigned short* __restrict__ W1p, const float* __restrict__ b1,
                                                    const unsigned short* __restrict__ W2p, const float* __restrict__ b2,
                                                    const unsigned short* __restrict__ W3p, const float* __restrict__ b3,
                                                    float* __restrict__ out) {
    __shared__ unsigned short As[16][264];
    __shared__ unsigned short Zs[16][264];
    int T = threadIdx.x;
    int lane = T & 63, wv = T >> 6;
    int nb = blockIdx.x * 16;
    int c4 = lane * 4;
    int n = nb + wv;
    int m = lane & 15, q = lane >> 4;
#pragma unroll 1
    for (int rep = 0; rep < 2; rep++) {
        asm volatile("" ::: "memory");
        if (n < N) {
            float4 v = *(const float4*)&h[(size_t)n * D + c4];
            As[wv][c4 + 0] = f2bf(v.x);
            As[wv][c4 + 1] = f2bf(v.y);
            As[wv][c4 + 2] = f2bf(v.z);
            As[wv][c4 + 3] = f2bf(v.w);
        } else {
            As[wv][c4 + 0] = 0; As[wv][c4 + 1] = 0; As[wv][c4 + 2] = 0; As[wv][c4 + 3] = 0;
        }
        __syncthreads();
        {
            float bv = b1[wv * 16 + m];
            f32x4 acc = (f32x4){bv, bv, bv, bv};
#pragma unroll
            for (int ks = 0; ks < 8; ks++) {
                bfrag af = *(const bfrag*)&As[m][ks * 32 + q * 8];
                bfrag bf = *(const bfrag*)&W1p[(((size_t)wv * 8 + ks) * 64 + lane) * 8];
                acc = __builtin_amdgcn_mfma_f32_16x16x32_bf16(af, bf, acc, 0, 0, 0);
            }
            int colg = wv * 16 + m;
#pragma unroll
            for (int reg = 0; reg < 4; reg++)
                Zs[q * 4 + reg][colg] = f2bf(fmaxf(acc[reg], 0.f));
        }
        __syncthreads();
        if (wv < 8) {
            float bv = b2[wv * 16 + m];
            f32x4 acc = (f32x4){bv, bv, bv, bv};
#pragma unroll
            for (int ks = 0; ks < 8; ks++) {
                bfrag af = *(const bfrag*)&Zs[m][ks * 32 + q * 8];
                bfrag bf = *(const bfrag*)&W2p[(((size_t)wv * 8 + ks) * 64 + lane) * 8];
                acc = __builtin_amdgcn_mfma_f32_16x16x32_bf16(af, bf, acc, 0, 0, 0);
            }
            int colg = wv * 16 + m;
#pragma unroll
            for (int reg = 0; reg < 4; reg++)
                As[q * 4 + reg][colg] = f2bf(fmaxf(acc[reg], 0.f));
        }
        __syncthreads();
        if (wv < 13) {
            int colg = wv * 16 + m;
            float bv = (colg < MC) ? b3[colg] : 0.f;
            f32x4 acc = (f32x4){bv, bv, bv, bv};
#pragma unroll
            for (int ks = 0; ks < 4; ks++) {
                bfrag af = *(const bfrag*)&As[m][ks * 32 + q * 8];
                bfrag bf = *(const bfrag*)&W3p[(((size_t)wv * 4 + ks) * 64 + lane) * 8];
                acc = __builtin_amdgcn_mfma_f32_16x16x32_bf16(af, bf, acc, 0, 0, 0);
            }
#pragma unroll
            for (int reg = 0; reg < 4; reg++) {
                int row = nb + q * 4 + reg;
                if (row < N && colg < MC) out[(size_t)row * MC + colg] = acc[reg];
            }
        }
        __syncthreads();
    }
}

// pooling stage 1 DOUBLED.
__global__ __launch_bounds__(256) void pool_k(const float* __restrict__ h, const int* __restrict__ batch,
                                              float* __restrict__ psum, float* __restrict__ pmax,
                                              int* __restrict__ cnt, int N) {
    int b = blockIdx.x;
    int sl = blockIdx.y;
    int c = threadIdx.x;
#pragma unroll 1
    for (int rep = 0; rep < 2; rep++) {
        asm volatile("" ::: "memory");
        int lo = 0, hi = N;
        while (lo < hi) { int mid = (lo + hi) >> 1; if (batch[mid] < b) lo = mid + 1; else hi = mid; }
        int s0 = lo;
        lo = 0; hi = N;
        while (lo < hi) { int mid = (lo + hi) >> 1; if (batch[mid] < b + 1) lo = mid + 1; else hi = mid; }
        int s1 = lo;
        int len = s1 - s0;
        int chunk = (len + PS - 1) / PS;
        int n0 = s0 + sl * chunk;
        int n1 = min(n0 + chunk, s1);
        float sum = 0.f, mx = -3.0e38f;
        for (int n = n0; n < n1; n++) {
            float v = h[(size_t)n * D + c];
            sum += v;
            mx = fmaxf(mx, v);
        }
        psum[(size_t)(b * PS + sl) * D + c] = sum;
        pmax[(size_t)(b * PS + sl) * D + c] = mx;
        if (c == 0 && sl == 0) cnt[b] = len;
    }
}

// graph heads DOUBLED.
__global__ __launch_bounds__(256) void heads_k(const float* __restrict__ psum, const float* __restrict__ pmax,
                                               const int* __restrict__ cnt,
                                               const float* __restrict__ chW1, const float* __restrict__ chb1,
                                               const float* __restrict__ chW2, const float* __restrict__ chb2,
                                               const float* __restrict__ chW3, const float* __restrict__ chb3,
                                               const float* __restrict__ tW1, const float* __restrict__ tb1,
                                               const float* __restrict__ tW2, const float* __restrict__ tb2,
                                               const float* __restrict__ dW1, const float* __restrict__ db1,
                                               const float* __restrict__ dW2, const float* __restrict__ db2,
                                               float* __restrict__ out_ch, float* __restrict__ out_t,
                                               float* __restrict__ out_d) {
    int b = blockIdx.x, sec = blockIdx.y, t = threadIdx.x;
    __shared__ float g[2 * D];
    __shared__ float z1[D];
    __shared__ float z2[128];
#pragma unroll 1
    for (int rep = 0; rep < 2; rep++) {
        asm volatile("" ::: "memory");
        float sum = 0.f, mx = -3.0e38f;
#pragma unroll
        for (int sl = 0; sl < PS; sl++) {
            sum += psum[(size_t)(b * PS + sl) * D + t];
            mx = fmaxf(mx, pmax[(size_t)(b * PS + sl) * D + t]);
        }
        int cn = cnt[b];
        float c = fmaxf((float)cn, 1.f);
        g[t] = sum / c;
        g[D + t] = (cn > 0) ? mx : 0.f;
        __syncthreads();
        if (sec == 0) {
            z1[t] = fmaxf(chb1[t] + dot_ilp(g, chW1, 2 * D, D, t), 0.f);
            __syncthreads();
            if (t < 128) z2[t] = fmaxf(chb2[t] + dot_ilp(z1, chW2, D, 128, t), 0.f);
            __syncthreads();
            if (t < MC) out_ch[b * MC + t] = chb3[t] + dot_ilp(z2, chW3, 128, MC, t);
        } else if (sec == 1) {
            if (t < 128) z1[t] = fmaxf(tb1[t] + dot_ilp(g, tW1, 2 * D, 128, t), 0.f);
            __syncthreads();
            if (t < NT) out_t[b * NT + t] = tb2[t] + dot_ilp(z1, tW2, 128, NT, t);
        } else {
            if (t < 64) z1[t] = fmaxf(db1[t] + dot_ilp(g, dW1, 2 * D, 64, t), 0.f);
            __syncthreads();
            if (t == 0) {
                float a = db2[0] + dot_ilp(z1, dW2, 64, 1, 0);
                out_d[b] = 100.f / (1.f + __expf(-a));
            }
        }
        __syncthreads();
    }
}

// ----------------------------------------------------------------
extern "C" void kernel_launch(void* const* d_in, const int* in_sizes, int n_in,
                              void* d_out, int out_size, void* d_ws, size_t ws_size,
                              hipStream_t stream) {
    const float* x     = (const float*)d_in[0];
    const int*   ei    = (const int*)d_in[1];
    const int*   batch = (const int*)d_in[2];
    const float* encW  = (const float*)d_in[3];
    const float* encb  = (const float*)d_in[4];
    const float* encls = (const float*)d_in[5];
    const float* enclb = (const float*)d_in[6];
    const float* Wl    = (const float*)d_in[7];
    const float* bl    = (const float*)d_in[8];
    const float* Wr    = (const float*)d_in[9];
    const float* br    = (const float*)d_in[10];
    const float* att   = (const float*)d_in[11];
    const float* gb    = (const float*)d_in[12];
    const float* gls   = (const float*)d_in[13];
    const float* glb   = (const float*)d_in[14];
    const float* cW1   = (const float*)d_in[15];
    const float* cb1   = (const float*)d_in[16];
    const float* cW2   = (const float*)d_in[17];
    const float* cb2   = (const float*)d_in[18];
    const float* cW3   = (const float*)d_in[19];
    const float* cb3   = (const float*)d_in[20];
    const float* chW1  = (const float*)d_in[21];
    const float* chb1  = (const float*)d_in[22];
    const float* chW2  = (const float*)d_in[23];
    const float* chb2  = (const float*)d_in[24];
    const float* chW3  = (const float*)d_in[25];
    const float* chb3  = (const float*)d_in[26];
    const float* tW1   = (const float*)d_in[27];
    const float* tb1   = (const float*)d_in[28];
    const float* tW2   = (const float*)d_in[29];
    const float* tb2   = (const float*)d_in[30];
    const float* dW1   = (const float*)d_in[31];
    const float* db1   = (const float*)d_in[32];
    const float* dW2   = (const float*)d_in[33];
    const float* db2   = (const float*)d_in[34];

    const int N = in_sizes[0] / DIN;
    const int E = in_sizes[1] / 2;
    const int* esrc = ei;
    const int* edst = ei + E;

    char* p = (char*)d_ws;
    auto carve = [&](size_t bytes) { char* r = p; p += (bytes + 255) & ~(size_t)255; return r; };
    int*            row_ptr = (int*)carve((size_t)(N + 1) * 4);
    int*            fill    = (int*)carve((size_t)N * 4);
    int*            deg     = (int*)carve((size_t)N * 4);
    int*            cnt     = (int*)carve((size_t)BG * 4);
    float*          psum    = (float*)carve((size_t)BG * PS * D * 4);
    float*          pmax    = (float*)carve((size_t)BG * PS * D * 4);
    int*            col     = (int*)carve((size_t)(E + N) * 4);
    unsigned short* Wp      = (unsigned short*)carve((size_t)NL * 2 * 65536 * 2);
    unsigned short* cW1p    = (unsigned short*)carve((size_t)16 * 8 * 64 * 8 * 2);
    unsigned short* cW2p    = (unsigned short*)carve((size_t)8 * 8 * 64 * 8 * 2);
    unsigned short* cW3p    = (unsigned short*)carve((size_t)13 * 4 * 64 * 8 * 2);
    float*          h       = (float*)carve((size_t)N * D * 4);
    unsigned short* xlA     = (unsigned short*)carve((size_t)N * D * 2);
    unsigned short* xrA     = (unsigned short*)carve((size_t)N * D * 2);
    unsigned short* xlB     = (unsigned short*)carve((size_t)N * D * 2);
    unsigned short* xrB     = (unsigned short*)carve((size_t)N * D * 2);
    (void)ws_size; (void)n_in; (void)out_size;

    const int ntiles16 = (N + 15) / 16;
    const int nblk4    = (N + 3) / 4;
    const int sblocks  = max(ntiles16, (E + N + 255) / 256);
    const int fblocks  = max((N + 3) / 4, max((E + 255) / 256, 384));

    hipMemsetAsync(deg, 0, (size_t)N * 4, stream);
    fused_init_k<<<fblocks, 256, 0, stream>>>(x, encW, encb, encls, enclb, h, N,
                                              edst, deg, E, Wl, Wr, Wp,
                                              cW1, cW1p, cW2, cW2p, cW3, cW3p);
    scan_k<<<1, 1024, 0, stream>>>(deg, row_ptr, fill, N);
    scatter_gemm0_k<<<sblocks, 256, 0, stream>>>(esrc, edst, fill, col, E, N, h,
                                                 Wp + 0, Wp + (size_t)65536,
                                                 bl + 0, br + 0, xlA, xrA);
    sortcol_k<<<nblk4, 256, 0, stream>>>(row_ptr, col, N);
    for (int l = 0; l < NL - 1; l++) {
        const unsigned short* xin_l = (l & 1) ? xlB : xlA;
        const unsigned short* xin_r = (l & 1) ? xrB : xrA;
        unsigned short* xout_l = (l & 1) ? xlA : xlB;
        unsigned short* xout_r = (l & 1) ? xrA : xrB;
        attn_k<<<nblk4, 256, 0, stream>>>(xin_l, xin_r, row_ptr, col, att + l * NH * NC,
                                          gb + l * D, gls + l * D, glb + l * D, h, l, N);
        gemm_lr_k<<<ntiles16, 256, 0, stream>>>(h,
                                                Wp + (size_t)((l + 1) * 2 + 0) * 65536,
                                                Wp + (size_t)((l + 1) * 2 + 1) * 65536,
                                                bl + (l + 1) * D, br + (l + 1) * D, xout_l, xout_r, N);
    }
    float* out = (float*)d_out;
    attn_k<<<nblk4, 256, 0, stream>>>(xlB, xrB, row_ptr, col, att + (NL - 1) * NH * NC,
                                      gb + (NL - 1) * D, gls + (NL - 1) * D, glb + (NL - 1) * D,
                                      h, NL - 1, N);
    colorhead_k<<<ntiles16, 1024, 0, stream>>>(h, N, cW1p, cb1, cW2p, cb2, cW3p, cb3, out);
    pool_k<<<dim3(BG, PS), 256, 0, stream>>>(h, batch, psum, pmax, cnt, N);
    heads_k<<<dim3(BG, 3), 256, 0, stream>>>(psum, pmax, cnt, chW1, chb1, chW2, chb2, chW3, chb3,
                                             tW1, tb1, tW2, tb2, dW1, db1, dW2, db2,
                                             out + (size_t)N * MC,
                                             out + (size_t)N * MC + BG * MC,
                                             out + (size_t)N * MC + BG * MC + BG * NT);
}

// Round 12
// 403.402 us; speedup vs baseline: 2.1390x; 2.1390x over previous
//
#include <hip/hip_runtime.h>
#include <hip/hip_bf16.h>

constexpr int DIN = 16;
constexpr int D   = 256;
constexpr int NH  = 8;
constexpr int NC  = 32;
constexpr int MC  = 200;
constexpr int NT  = 8;
constexpr int BG  = 16;
constexpr int NL  = 6;
constexpr int PS  = 16;   // pool slices per graph
constexpr float NEG = 0.2f;

typedef __attribute__((ext_vector_type(8))) short bfrag;
typedef __attribute__((ext_vector_type(4))) float f32x4;

__device__ inline unsigned short f2bf(float f) {
    unsigned int u = __float_as_uint(f);
    u += 0x7FFFu + ((u >> 16) & 1u);
    return (unsigned short)(u >> 16);
}
__device__ inline float bf2f(unsigned short u) {
    return __uint_as_float((unsigned int)u << 16);
}

// ---------------- device helpers ----------------

__device__ inline void enc_node(const float* x, const float* W, const float* b, const float* ls,
                                const float* lb, float* h, int n, int lane) {
    int c4 = lane * 4;
    float xs[DIN];
#pragma unroll
    for (int k = 0; k < DIN; k += 4) {
        float4 xv = *(const float4*)&x[n * DIN + k];
        xs[k] = xv.x; xs[k + 1] = xv.y; xs[k + 2] = xv.z; xs[k + 3] = xv.w;
    }
    float4 a = *(const float4*)&b[c4];
#pragma unroll
    for (int k = 0; k < DIN; k++) {
        float4 wv = *(const float4*)&W[k * D + c4];
        a.x = fmaf(xs[k], wv.x, a.x);
        a.y = fmaf(xs[k], wv.y, a.y);
        a.z = fmaf(xs[k], wv.z, a.z);
        a.w = fmaf(xs[k], wv.w, a.w);
    }
    float s = a.x + a.y + a.z + a.w;
#pragma unroll
    for (int msk = 1; msk <= 32; msk <<= 1) s += __shfl_xor(s, msk);
    float mu = s * (1.f / D);
    float4 dv = make_float4(a.x - mu, a.y - mu, a.z - mu, a.w - mu);
    float v2 = dv.x * dv.x + dv.y * dv.y + dv.z * dv.z + dv.w * dv.w;
#pragma unroll
    for (int msk = 1; msk <= 32; msk <<= 1) v2 += __shfl_xor(v2, msk);
    float rstd = rsqrtf(v2 * (1.f / D) + 1e-5f);
    float4 lsv = *(const float4*)&ls[c4];
    float4 lbv = *(const float4*)&lb[c4];
    float4 y = make_float4(fmaxf(dv.x * rstd * lsv.x + lbv.x, 0.f),
                           fmaxf(dv.y * rstd * lsv.y + lbv.y, 0.f),
                           fmaxf(dv.z * rstd * lsv.z + lbv.z, 0.f),
                           fmaxf(dv.w * rstd * lsv.w + lbv.w, 0.f));
    *(float4*)&h[(size_t)n * D + c4] = y;
}

// attn for one node (one full wave); depth-4 software pipeline.
// No running-max: logits bounded << exp overflow (order-free sums).
__device__ inline float4 attn_compute(const unsigned short* xl, const unsigned short* xr,
                                      const int* row_ptr, const int* col, const float* att,
                                      const float* gb, const float* gls, const float* glb,
                                      const float* h, int layer, int n, int lane) {
    int c4 = lane * 4;
    ushort4 xr4 = *(const ushort4*)&xr[(size_t)n * D + c4];
    float4 xrv = make_float4(bf2f(xr4.x), bf2f(xr4.y), bf2f(xr4.z), bf2f(xr4.w));
    float4 av  = *(const float4*)&att[c4];
    int beg = row_ptr[n], end = row_ptr[n + 1];
    int deg = end - beg;
    int myc = col[beg + min(lane, deg - 1)];
    float l = 0.f;
    float4 acc = make_float4(0.f, 0.f, 0.f, 0.f);
    auto loadx = [&](int i) -> ushort4 {
        if (i < deg) {
            int s = (i < 64) ? __shfl(myc, i) : col[beg + i];
            return *(const ushort4*)&xl[(size_t)s * D + c4];
        }
        return make_ushort4(0, 0, 0, 0);
    };
    auto step = [&](ushort4 x4) {
        float4 xlv = make_float4(bf2f(x4.x), bf2f(x4.y), bf2f(x4.z), bf2f(x4.w));
        float sx = xlv.x + xrv.x; sx = sx > 0.f ? sx : NEG * sx;
        float sy = xlv.y + xrv.y; sy = sy > 0.f ? sy : NEG * sy;
        float sz = xlv.z + xrv.z; sz = sz > 0.f ? sz : NEG * sz;
        float sw = xlv.w + xrv.w; sw = sw > 0.f ? sw : NEG * sw;
        float z = av.x * sx + av.y * sy + av.z * sz + av.w * sw;
        z += __shfl_xor(z, 1); z += __shfl_xor(z, 2); z += __shfl_xor(z, 4);
        float p = __expf(z);
        l += p;
        acc.x = fmaf(p, xlv.x, acc.x);
        acc.y = fmaf(p, xlv.y, acc.y);
        acc.z = fmaf(p, xlv.z, acc.z);
        acc.w = fmaf(p, xlv.w, acc.w);
    };
    ushort4 b0 = loadx(0), b1 = loadx(1), b2 = loadx(2), b3 = loadx(3);
    int e = 0;
    for (; e + 4 <= deg; e += 4) {
        ushort4 n0 = loadx(e + 4), n1 = loadx(e + 5), n2 = loadx(e + 6), n3 = loadx(e + 7);
        step(b0); step(b1); step(b2); step(b3);
        b0 = n0; b1 = n1; b2 = n2; b3 = n3;
    }
    if (e + 0 < deg) step(b0);
    if (e + 1 < deg) step(b1);
    if (e + 2 < deg) step(b2);
    float4 gbv = *(const float4*)&gb[c4];
    float rl = 1.f / l;
    float4 o = make_float4(acc.x * rl + gbv.x, acc.y * rl + gbv.y,
                           acc.z * rl + gbv.z, acc.w * rl + gbv.w);
    float s = o.x + o.y + o.z + o.w;
#pragma unroll
    for (int msk = 1; msk <= 32; msk <<= 1) s += __shfl_xor(s, msk);
    float mu = s * (1.f / D);
    float4 dv = make_float4(o.x - mu, o.y - mu, o.z - mu, o.w - mu);
    float v2 = dv.x * dv.x + dv.y * dv.y + dv.z * dv.z + dv.w * dv.w;
#pragma unroll
    for (int msk = 1; msk <= 32; msk <<= 1) v2 += __shfl_xor(v2, msk);
    float rstd = rsqrtf(v2 * (1.f / D) + 1e-5f);
    float4 glsv = *(const float4*)&gls[c4];
    float4 glbv = *(const float4*)&glb[c4];
    float y0 = dv.x * rstd * glsv.x + glbv.x;
    float y1 = dv.y * rstd * glsv.y + glbv.y;
    float y2 = dv.z * rstd * glsv.z + glbv.z;
    float y3 = dv.w * rstd * glsv.w + glbv.w;
    y0 = y0 > 0.f ? y0 : expm1f(y0);
    y1 = y1 > 0.f ? y1 : expm1f(y1);
    y2 = y2 > 0.f ? y2 : expm1f(y2);
    y3 = y3 > 0.f ? y3 : expm1f(y3);
    float4 prev = make_float4(0.f, 0.f, 0.f, 0.f);
    if (layer > 0) prev = *(const float4*)&h[(size_t)n * D + c4];
    return make_float4(prev.x + y0, prev.y + y1, prev.z + y2, prev.w + y3);
}

// MFMA GEMM on a 16-row tile, one wave handles one 16-col tile (ctg).
__device__ inline void gemm_one_ct(const unsigned short (*As)[264],
                                   const unsigned short* WpL, const unsigned short* WpR,
                                   const float* bl, const float* br,
                                   unsigned short* xl, unsigned short* xr,
                                   int N, int nb, int ctg, int lane) {
    int m = lane & 15, q = lane >> 4;
    float bLv = bl[ctg * 16 + m];
    float bRv = br[ctg * 16 + m];
    f32x4 accL = (f32x4){bLv, bLv, bLv, bLv};
    f32x4 accR = (f32x4){bRv, bRv, bRv, bRv};
#pragma unroll
    for (int ks = 0; ks < 8; ks++) {
        bfrag af = *(const bfrag*)&As[m][ks * 32 + q * 8];
        size_t off = (((size_t)ctg * 8 + ks) * 64 + lane) * 8;
        bfrag bL = *(const bfrag*)&WpL[off];
        bfrag bR = *(const bfrag*)&WpR[off];
        accL = __builtin_amdgcn_mfma_f32_16x16x32_bf16(af, bL, accL, 0, 0, 0);
        accR = __builtin_amdgcn_mfma_f32_16x16x32_bf16(af, bR, accR, 0, 0, 0);
    }
    int colg = ctg * 16 + m;
#pragma unroll
    for (int reg = 0; reg < 4; reg++) {
        int row = nb + q * 4 + reg;
        if (row < N) {
            xl[(size_t)row * D + colg] = f2bf(accL[reg]);
            xr[(size_t)row * D + colg] = f2bf(accR[reg]);
        }
    }
}

// 4-wave variant (wave w owns col-tiles w*4..w*4+3)
__device__ inline void gemm_core(const unsigned short (*As)[264],
                                 const unsigned short* WpL, const unsigned short* WpR,
                                 const float* bl, const float* br,
                                 unsigned short* xl, unsigned short* xr, int N, int nb, int T) {
    int lane = T & 63, w = T >> 6;
#pragma unroll
    for (int ct = 0; ct < 4; ct++)
        gemm_one_ct(As, WpL, WpR, bl, br, xl, xr, N, nb, w * 4 + ct, lane);
}

// generic 16-row MFMA tile for the graph heads: A is bf16 [16][LDA] in LDS,
// Wp packed by repack_gen layout, K = NKS*32 unrolled at compile time.
template<int NKS>
__device__ inline f32x4 head_mma(const unsigned short* A, int LDA,
                                 const unsigned short* Wp, int ct,
                                 const float* bias, int NCOL, int lane) {
    int m = lane & 15, q = lane >> 4;
    (void)q;
    int colg = ct * 16 + m;
    float bv = (colg < NCOL) ? bias[colg] : 0.f;
    f32x4 acc = (f32x4){bv, bv, bv, bv};
#pragma unroll
    for (int ks = 0; ks < NKS; ks++) {
        bfrag af = *(const bfrag*)&A[m * LDA + ks * 32 + (lane >> 4) * 8];
        bfrag bf = *(const bfrag*)&Wp[(((size_t)ct * NKS + ks) * 64 + lane) * 8];
        acc = __builtin_amdgcn_mfma_f32_16x16x32_bf16(af, bf, acc, 0, 0, 0);
    }
    return acc;   // row = (lane>>4)*4 + reg, col = ct*16 + (lane&15)
}

__device__ inline void repack_attn_one(const float* Wl, const float* Wr, unsigned short* Wp, int tid) {
    int lane = tid & 63;
    int r1 = tid >> 6;
    int ks = r1 & 7;
    int r2 = r1 >> 3;
    int ct = r2 & 15;
    int mi = r2 >> 4;
    int layer = mi >> 1, mat = mi & 1;
    const float* W = (mat == 0 ? Wl : Wr) + (size_t)layer * D * D;
    int n = ct * 16 + (lane & 15);
    int kb = ks * 32 + (lane >> 4) * 8;
    size_t base = (((size_t)(mi * 16 + ct) * 8 + ks) * 64 + lane) * 8;
#pragma unroll
    for (int j = 0; j < 8; j++) Wp[base + j] = f2bf(W[(size_t)(kb + j) * D + n]);
}

__device__ inline void repack_gen_one(const float* W, unsigned short* Wp, int K, int NCOL, int nks, int tid) {
    int lane = tid & 63;
    int r = tid >> 6;
    int ks = r % nks;
    int ct = r / nks;
    int n = ct * 16 + (lane & 15);
    int kb = ks * 32 + (lane >> 4) * 8;
    size_t base = (((size_t)ct * nks + ks) * 64 + lane) * 8;
#pragma unroll
    for (int j = 0; j < 8; j++) {
        int k = kb + j;
        Wp[base + j] = (n < NCOL && k < K) ? f2bf(W[(size_t)k * NCOL + n]) : (unsigned short)0;
    }
}

// ---------------- kernels ----------------

// encoder + edge count + all weight repacks (incl. graph-head weights), fused.
__global__ __launch_bounds__(256) void fused_init_k(const float* __restrict__ x, const float* __restrict__ encW,
                                                    const float* __restrict__ encb, const float* __restrict__ encls,
                                                    const float* __restrict__ enclb, float* __restrict__ h, int N,
                                                    const int* __restrict__ dst, int* __restrict__ deg, int E,
                                                    const float* __restrict__ Wl, const float* __restrict__ Wr,
                                                    unsigned short* __restrict__ Wp,
                                                    const float* __restrict__ cW1, unsigned short* __restrict__ cW1p,
                                                    const float* __restrict__ cW2, unsigned short* __restrict__ cW2p,
                                                    const float* __restrict__ cW3, unsigned short* __restrict__ cW3p,
                                                    const float* __restrict__ chW1, unsigned short* __restrict__ chW1p,
                                                    const float* __restrict__ chW2, unsigned short* __restrict__ chW2p,
                                                    const float* __restrict__ chW3, unsigned short* __restrict__ chW3p,
                                                    const float* __restrict__ tW1, unsigned short* __restrict__ tW1p,
                                                    const float* __restrict__ tW2, unsigned short* __restrict__ tW2p,
                                                    const float* __restrict__ dW1, unsigned short* __restrict__ dW1p) {
    int gid = blockIdx.x * 256 + threadIdx.x;
    int lane = threadIdx.x & 63;
    int n = blockIdx.x * 4 + (threadIdx.x >> 6);
    if (n < N) enc_node(x, encW, encb, encls, enclb, h, n, lane);
    if (gid < E) atomicAdd(&deg[dst[gid]], 1);
    if (gid < NL * 2 * 16 * 8 * 64) repack_attn_one(Wl, Wr, Wp, gid);
    if (gid < 16 * 8 * 64) repack_gen_one(cW1, cW1p, D, D, 8, gid);
    if (gid < 8 * 8 * 64)  repack_gen_one(cW2, cW2p, D, 128, 8, gid);
    if (gid < 13 * 4 * 64) repack_gen_one(cW3, cW3p, 128, MC, 4, gid);
    // graph-head packs on disjoint gid ranges (spread across later blocks)
    int g2 = gid - NL * 2 * 16 * 8 * 64;
    if (g2 >= 0 && g2 < 16 * 16 * 64) repack_gen_one(chW1, chW1p, 2 * D, D, 16, g2);
    g2 -= 16 * 16 * 64;
    if (g2 >= 0 && g2 < 8 * 8 * 64)   repack_gen_one(chW2, chW2p, D, 128, 8, g2);
    g2 -= 8 * 8 * 64;
    if (g2 >= 0 && g2 < 13 * 4 * 64)  repack_gen_one(chW3, chW3p, 128, MC, 4, g2);
    g2 -= 13 * 4 * 64;
    if (g2 >= 0 && g2 < 8 * 16 * 64)  repack_gen_one(tW1, tW1p, 2 * D, 128, 16, g2);
    g2 -= 8 * 16 * 64;
    if (g2 >= 0 && g2 < 1 * 4 * 64)   repack_gen_one(tW2, tW2p, 128, NT, 4, g2);
    g2 -= 1 * 4 * 64;
    if (g2 >= 0 && g2 < 4 * 16 * 64)  repack_gen_one(dW1, dW1p, 2 * D, 64, 16, g2);
}

// single-block scan. deg holds in-degree only; +1 accounts for the self loop.
__global__ __launch_bounds__(1024) void scan_k(const int* __restrict__ deg, int* __restrict__ row_ptr,
                                               int* __restrict__ fill, int N) {
    __shared__ int sd[1024];
    int t = threadIdx.x;
    int chunk = (N + 1023) >> 10;
    int lo = t * chunk, hi = min(lo + chunk, N);
    int s = 0;
    for (int i = lo; i < hi; i++) s += deg[i] + 1;
    sd[t] = s;
    __syncthreads();
    for (int off = 1; off < 1024; off <<= 1) {
        int v = (t >= off) ? sd[t - off] : 0;
        __syncthreads();
        sd[t] += v;
        __syncthreads();
    }
    int run = (t > 0) ? sd[t - 1] : 0;
    for (int i = lo; i < hi; i++) {
        row_ptr[i] = run; fill[i] = run;
        run += deg[i] + 1;
    }
    if (t == 1023) row_ptr[N] = sd[1023];
}

// scatter + layer-0 GEMM
__global__ __launch_bounds__(256) void scatter_gemm0_k(const int* __restrict__ src, const int* __restrict__ dst,
                                                       int* __restrict__ fill, int* __restrict__ col, int E, int N,
                                                       const float* __restrict__ h,
                                                       const unsigned short* __restrict__ WpL,
                                                       const unsigned short* __restrict__ WpR,
                                                       const float* __restrict__ bl, const float* __restrict__ br,
                                                       unsigned short* __restrict__ xl, unsigned short* __restrict__ xr) {
    __shared__ unsigned short As[16][264];
    int T = threadIdx.x;
    int tt = blockIdx.x;
    int ntiles = (N + 15) >> 4;
    if (tt < ntiles) {
        int nb = tt * 16;
#pragma unroll
        for (int r = 0; r < 16; r++) {
            int row = nb + r;
            float v = (row < N) ? h[(size_t)row * D + T] : 0.f;
            As[r][T] = f2bf(v);
        }
        __syncthreads();
        gemm_core(As, WpL, WpR, bl, br, xl, xr, N, nb, T);
    }
    for (int e = blockIdx.x * 256 + T; e < E + N; e += gridDim.x * 256) {
        if (e < E) {
            int p = atomicAdd(&fill[dst[e]], 1);
            col[p] = src[e];
        } else {
            int n = e - E;
            int p = atomicAdd(&fill[n], 1);
            col[p] = n;
        }
    }
}

// sort each CSR row's columns ascending (wave-level bitonic; deg<=64 for Poisson(17)).
// Legal because the no-max softmax sums are order-free.
__global__ __launch_bounds__(256) void sortcol_k(const int* __restrict__ row_ptr,
                                                 int* __restrict__ col, int N) {
    int lane = threadIdx.x & 63;
    int n = blockIdx.x * 4 + (threadIdx.x >> 6);
    if (n >= N) return;
    int beg = row_ptr[n], deg = row_ptr[n + 1] - beg;
    if (deg > 64) return;   // unsorted fallback — still correct
    int key = (lane < deg) ? col[beg + lane] : 0x7FFFFFFF;
#pragma unroll
    for (int k = 2; k <= 64; k <<= 1) {
#pragma unroll
        for (int j = k >> 1; j > 0; j >>= 1) {
            int other = __shfl_xor(key, j);
            bool up = ((lane & k) == 0);
            bool takeMin = (((lane & j) == 0) == up);
            key = takeMin ? min(key, other) : max(key, other);
        }
    }
    if (lane < deg) col[beg + lane] = key;
}

// attention-only kernel: 256 threads = 4 waves, ONE node per wave, no LDS, no barriers.
__global__ __launch_bounds__(256, 4) void attn_k(const unsigned short* __restrict__ xl_in,
                                                 const unsigned short* __restrict__ xr_in,
                                                 const int* __restrict__ row_ptr, const int* __restrict__ col,
                                                 const float* __restrict__ att, const float* __restrict__ gb,
                                                 const float* __restrict__ gls, const float* __restrict__ glb,
                                                 float* __restrict__ h, int layer, int N) {
    int T = threadIdx.x;
    int lane = T & 63, wv = T >> 6;
    int n = blockIdx.x * 4 + wv;
    if (n >= N) return;
    float4 res = attn_compute(xl_in, xr_in, row_ptr, col, att, gb, gls, glb, h, layer, n, lane);
    *(float4*)&h[(size_t)n * D + lane * 4] = res;
}

// GEMM-only kernel: reads h (f32), produces xl/xr (bf16) for the NEXT layer.
__global__ __launch_bounds__(256, 4) void gemm_lr_k(const float* __restrict__ h,
                                                    const unsigned short* __restrict__ WpL,
                                                    const unsigned short* __restrict__ WpR,
                                                    const float* __restrict__ bl, const float* __restrict__ br,
                                                    unsigned short* __restrict__ xl, unsigned short* __restrict__ xr,
                                                    int N) {
    __shared__ unsigned short As[16][264];
    int T = threadIdx.x;
    int nb = blockIdx.x * 16;
#pragma unroll
    for (int r = 0; r < 16; r++) {
        int row = nb + r;
        float v = (row < N) ? h[(size_t)row * D + T] : 0.f;
        As[r][T] = f2bf(v);
    }
    __syncthreads();
    gemm_core(As, WpL, WpR, bl, br, xl, xr, N, nb, T);
}

// color-head MLP (MFMA), reads h: 1024 threads, 16 nodes/block.
__global__ __launch_bounds__(1024) void colorhead_k(const float* __restrict__ h, int N,
                                                    const unsigned short* __restrict__ W1p, const float* __restrict__ b1,
                                                    const unsigned short* __restrict__ W2p, const float* __restrict__ b2,
                                                    const unsigned short* __restrict__ W3p, const float* __restrict__ b3,
                                                    float* __restrict__ out) {
    __shared__ unsigned short As[16][264];
    __shared__ unsigned short Zs[16][264];
    int T = threadIdx.x;
    int lane = T & 63, wv = T >> 6;
    int nb = blockIdx.x * 16;
    int c4 = lane * 4;
    int n = nb + wv;
    if (n < N) {
        float4 v = *(const float4*)&h[(size_t)n * D + c4];
        As[wv][c4 + 0] = f2bf(v.x);
        As[wv][c4 + 1] = f2bf(v.y);
        As[wv][c4 + 2] = f2bf(v.z);
        As[wv][c4 + 3] = f2bf(v.w);
    } else {
        As[wv][c4 + 0] = 0; As[wv][c4 + 1] = 0; As[wv][c4 + 2] = 0; As[wv][c4 + 3] = 0;
    }
    __syncthreads();
    int m = lane & 15, q = lane >> 4;
    {
        float bv = b1[wv * 16 + m];
        f32x4 acc = (f32x4){bv, bv, bv, bv};
#pragma unroll
        for (int ks = 0; ks < 8; ks++) {
            bfrag af = *(const bfrag*)&As[m][ks * 32 + q * 8];
            bfrag bf = *(const bfrag*)&W1p[(((size_t)wv * 8 + ks) * 64 + lane) * 8];
            acc = __builtin_amdgcn_mfma_f32_16x16x32_bf16(af, bf, acc, 0, 0, 0);
        }
        int colg = wv * 16 + m;
#pragma unroll
        for (int reg = 0; reg < 4; reg++)
            Zs[q * 4 + reg][colg] = f2bf(fmaxf(acc[reg], 0.f));
    }
    __syncthreads();
    if (wv < 8) {
        float bv = b2[wv * 16 + m];
        f32x4 acc = (f32x4){bv, bv, bv, bv};
#pragma unroll
        for (int ks = 0; ks < 8; ks++) {
            bfrag af = *(const bfrag*)&Zs[m][ks * 32 + q * 8];
            bfrag bf = *(const bfrag*)&W2p[(((size_t)wv * 8 + ks) * 64 + lane) * 8];
            acc = __builtin_amdgcn_mfma_f32_16x16x32_bf16(af, bf, acc, 0, 0, 0);
        }
        int colg = wv * 16 + m;
#pragma unroll
        for (int reg = 0; reg < 4; reg++)
            As[q * 4 + reg][colg] = f2bf(fmaxf(acc[reg], 0.f));
    }
    __syncthreads();
    if (wv < 13) {
        int colg = wv * 16 + m;
        float bv = (colg < MC) ? b3[colg] : 0.f;
        f32x4 acc = (f32x4){bv, bv, bv, bv};
#pragma unroll
        for (int ks = 0; ks < 4; ks++) {
            bfrag af = *(const bfrag*)&As[m][ks * 32 + q * 8];
            bfrag bf = *(const bfrag*)&W3p[(((size_t)wv * 4 + ks) * 64 + lane) * 8];
            acc = __builtin_amdgcn_mfma_f32_16x16x32_bf16(af, bf, acc, 0, 0, 0);
        }
#pragma unroll
        for (int reg = 0; reg < 4; reg++) {
            int row = nb + q * 4 + reg;
            if (row < N && colg < MC) out[(size_t)row * MC + colg] = acc[reg];
        }
    }
}

// pooling stage 1 (256 blocks: 16 graphs x 16 slices); 4-way unrolled column walk
__global__ __launch_bounds__(256) void pool_k(const float* __restrict__ h, const int* __restrict__ batch,
                                              float* __restrict__ psum, float* __restrict__ pmax,
                                              int* __restrict__ cnt, int N) {
    int b = blockIdx.x;
    int sl = blockIdx.y;
    int c = threadIdx.x;
    int lo = 0, hi = N;
    while (lo < hi) { int mid = (lo + hi) >> 1; if (batch[mid] < b) lo = mid + 1; else hi = mid; }
    int s0 = lo;
    lo = 0; hi = N;
    while (lo < hi) { int mid = (lo + hi) >> 1; if (batch[mid] < b + 1) lo = mid + 1; else hi = mid; }
    int s1 = lo;
    int len = s1 - s0;
    int chunk = (len + PS - 1) / PS;
    int n0 = s0 + sl * chunk;
    int n1 = min(n0 + chunk, s1);
    float a0 = 0.f, a1 = 0.f, a2 = 0.f, a3 = 0.f;
    float m0 = -3.0e38f, m1 = -3.0e38f, m2 = -3.0e38f, m3 = -3.0e38f;
    int n = n0;
    for (; n + 4 <= n1; n += 4) {
        float v0 = h[(size_t)(n + 0) * D + c];
        float v1 = h[(size_t)(n + 1) * D + c];
        float v2 = h[(size_t)(n + 2) * D + c];
        float v3 = h[(size_t)(n + 3) * D + c];
        a0 += v0; a1 += v1; a2 += v2; a3 += v3;
        m0 = fmaxf(m0, v0); m1 = fmaxf(m1, v1);
        m2 = fmaxf(m2, v2); m3 = fmaxf(m3, v3);
    }
    for (; n < n1; n++) {
        float v = h[(size_t)n * D + c];
        a0 += v; m0 = fmaxf(m0, v);
    }
    float sum = (a0 + a1) + (a2 + a3);
    float mx = fmaxf(fmaxf(m0, m1), fmaxf(m2, m3));
    psum[(size_t)(b * PS + sl) * D + c] = sum;
    pmax[(size_t)(b * PS + sl) * D + c] = mx;
    if (c == 0 && sl == 0) cnt[b] = len;
}

// graph heads via MFMA: 3 blocks (chromatic / type / difficulty), 1024 threads each.
__global__ __launch_bounds__(1024) void gheads_k(const float* __restrict__ psum, const float* __restrict__ pmax,
                                                 const int* __restrict__ cnt,
                                                 const unsigned short* __restrict__ chW1p, const float* __restrict__ chb1,
                                                 const unsigned short* __restrict__ chW2p, const float* __restrict__ chb2,
                                                 const unsigned short* __restrict__ chW3p, const float* __restrict__ chb3,
                                                 const unsigned short* __restrict__ tW1p, const float* __restrict__ tb1,
                                                 const unsigned short* __restrict__ tW2p, const float* __restrict__ tb2,
                                                 const unsigned short* __restrict__ dW1p, const float* __restrict__ db1,
                                                 const float* __restrict__ dW2, const float* __restrict__ db2,
                                                 float* __restrict__ out_ch, float* __restrict__ out_t,
                                                 float* __restrict__ out_d) {
    __shared__ unsigned short Gs[16][520];   // g = [mean || max], bf16
    __shared__ unsigned short Z1[16][264];
    __shared__ unsigned short Z2[16][136];
    __shared__ float Zd[16][68];
    int T = threadIdx.x;
    int sec = blockIdx.x;
    // assemble g (16 graphs x 512)
    for (int i = T; i < 16 * 512; i += 1024) {
        int b = i >> 9, c = i & 511;
        bool isMean = c < 256;
        int ch = c & 255;
        float acc = isMean ? 0.f : -3.0e38f;
#pragma unroll
        for (int sl = 0; sl < PS; sl++) {
            float v = isMean ? psum[(size_t)(b * PS + sl) * D + ch]
                             : pmax[(size_t)(b * PS + sl) * D + ch];
            acc = isMean ? (acc + v) : fmaxf(acc, v);
        }
        int cn = cnt[b];
        float v = isMean ? (acc / fmaxf((float)cn, 1.f)) : ((cn > 0) ? acc : 0.f);
        Gs[b][c] = f2bf(v);
    }
    __syncthreads();
    int lane = T & 63, wv = T >> 6;
    int m = lane & 15, q = lane >> 4;
    if (sec == 0) {
        {
            f32x4 acc = head_mma<16>(&Gs[0][0], 520, chW1p, wv, chb1, 256, lane);
            int colg = wv * 16 + m;
#pragma unroll
            for (int r = 0; r < 4; r++)
                Z1[q * 4 + r][colg] = f2bf(fmaxf(acc[r], 0.f));
        }
        __syncthreads();
        if (wv < 8) {
            f32x4 acc = head_mma<8>(&Z1[0][0], 264, chW2p, wv, chb2, 128, lane);
            int colg = wv * 16 + m;
#pragma unroll
            for (int r = 0; r < 4; r++)
                Z2[q * 4 + r][colg] = f2bf(fmaxf(acc[r], 0.f));
        }
        __syncthreads();
        if (wv < 13) {
            f32x4 acc = head_mma<4>(&Z2[0][0], 136, chW3p, wv, chb3, MC, lane);
            int colg = wv * 16 + m;
#pragma unroll
            for (int r = 0; r < 4; r++)
                if (colg < MC) out_ch[(q * 4 + r) * MC + colg] = acc[r];
        }
    } else if (sec == 1) {
        if (wv < 8) {
            f32x4 acc = head_mma<16>(&Gs[0][0], 520, tW1p, wv, tb1, 128, lane);
            int colg = wv * 16 + m;
#pragma unroll
            for (int r = 0; r < 4; r++)
                Z1[q * 4 + r][colg] = f2bf(fmaxf(acc[r], 0.f));
        }
        __syncthreads();
        if (wv == 0) {
            f32x4 acc = head_mma<4>(&Z1[0][0], 264, tW2p, 0, tb2, NT, lane);
#pragma unroll
            for (int r = 0; r < 4; r++)
                if (m < NT) out_t[(q * 4 + r) * NT + m] = acc[r];
        }
    } else {
        if (wv < 4) {
            f32x4 acc = head_mma<16>(&Gs[0][0], 520, dW1p, wv, db1, 64, lane);
            int colg = wv * 16 + m;
#pragma unroll
            for (int r = 0; r < 4; r++)
                Zd[q * 4 + r][colg] = fmaxf(acc[r], 0.f);
        }
        __syncthreads();
        if (wv == 0) {
            int g = lane >> 2, j0 = lane & 3;
            float s = 0.f;
#pragma unroll
            for (int j = 0; j < 16; j++) s = fmaf(Zd[g][j0 + 4 * j], dW2[j0 + 4 * j], s);
            s += __shfl_xor(s, 1);
            s += __shfl_xor(s, 2);
            if (j0 == 0) {
                float a = db2[0] + s;
                out_d[g] = 100.f / (1.f + __expf(-a));
            }
        }
    }
}

// ----------------------------------------------------------------
extern "C" void kernel_launch(void* const* d_in, const int* in_sizes, int n_in,
                              void* d_out, int out_size, void* d_ws, size_t ws_size,
                              hipStream_t stream) {
    const float* x     = (const float*)d_in[0];
    const int*   ei    = (const int*)d_in[1];
    const int*   batch = (const int*)d_in[2];
    const float* encW  = (const float*)d_in[3];
    const float* encb  = (const float*)d_in[4];
    const float* encls = (const float*)d_in[5];
    const float* enclb = (const float*)d_in[6];
    const float* Wl    = (const float*)d_in[7];
    const float* bl    = (const float*)d_in[8];
    const float* Wr    = (const float*)d_in[9];
    const float* br    = (const float*)d_in[10];
    const float* att   = (const float*)d_in[11];
    const float* gb    = (const float*)d_in[12];
    const float* gls   = (const float*)d_in[13];
    const float* glb   = (const float*)d_in[14];
    const float* cW1   = (const float*)d_in[15];
    const float* cb1   = (const float*)d_in[16];
    const float* cW2   = (const float*)d_in[17];
    const float* cb2   = (const float*)d_in[18];
    const float* cW3   = (const float*)d_in[19];
    const float* cb3   = (const float*)d_in[20];
    const float* chW1  = (const float*)d_in[21];
    const float* chb1  = (const float*)d_in[22];
    const float* chW2  = (const float*)d_in[23];
    const float* chb2  = (const float*)d_in[24];
    const float* chW3  = (const float*)d_in[25];
    const float* chb3  = (const float*)d_in[26];
    const float* tW1   = (const float*)d_in[27];
    const float* tb1   = (const float*)d_in[28];
    const float* tW2   = (const float*)d_in[29];
    const float* tb2   = (const float*)d_in[30];
    const float* dW1   = (const float*)d_in[31];
    const float* db1   = (const float*)d_in[32];
    const float* dW2   = (const float*)d_in[33];
    const float* db2   = (const float*)d_in[34];

    const int N = in_sizes[0] / DIN;
    const int E = in_sizes[1] / 2;
    const int* esrc = ei;
    const int* edst = ei + E;

    char* p = (char*)d_ws;
    auto carve = [&](size_t bytes) { char* r = p; p += (bytes + 255) & ~(size_t)255; return r; };
    int*            row_ptr = (int*)carve((size_t)(N + 1) * 4);
    int*            fill    = (int*)carve((size_t)N * 4);
    int*            deg     = (int*)carve((size_t)N * 4);
    int*            cnt     = (int*)carve((size_t)BG * 4);
    float*          psum    = (float*)carve((size_t)BG * PS * D * 4);
    float*          pmax    = (float*)carve((size_t)BG * PS * D * 4);
    int*            col     = (int*)carve((size_t)(E + N) * 4);
    unsigned short* Wp      = (unsigned short*)carve((size_t)NL * 2 * 65536 * 2);
    unsigned short* cW1p    = (unsigned short*)carve((size_t)16 * 8 * 64 * 8 * 2);
    unsigned short* cW2p    = (unsigned short*)carve((size_t)8 * 8 * 64 * 8 * 2);
    unsigned short* cW3p    = (unsigned short*)carve((size_t)13 * 4 * 64 * 8 * 2);
    unsigned short* chW1p   = (unsigned short*)carve((size_t)16 * 16 * 64 * 8 * 2);
    unsigned short* chW2p   = (unsigned short*)carve((size_t)8 * 8 * 64 * 8 * 2);
    unsigned short* chW3p   = (unsigned short*)carve((size_t)13 * 4 * 64 * 8 * 2);
    unsigned short* tW1p    = (unsigned short*)carve((size_t)8 * 16 * 64 * 8 * 2);
    unsigned short* tW2p    = (unsigned short*)carve((size_t)1 * 4 * 64 * 8 * 2);
    unsigned short* dW1p    = (unsigned short*)carve((size_t)4 * 16 * 64 * 8 * 2);
    float*          h       = (float*)carve((size_t)N * D * 4);
    unsigned short* xlA     = (unsigned short*)carve((size_t)N * D * 2);
    unsigned short* xrA     = (unsigned short*)carve((size_t)N * D * 2);
    unsigned short* xlB     = (unsigned short*)carve((size_t)N * D * 2);
    unsigned short* xrB     = (unsigned short*)carve((size_t)N * D * 2);
    (void)ws_size; (void)n_in; (void)out_size;

    const int ntiles16 = (N + 15) / 16;
    const int nblk4    = (N + 3) / 4;
    const int sblocks  = max(ntiles16, (E + N + 255) / 256);
    const int fblocks  = max((N + 3) / 4, max((E + 255) / 256, 576));

    hipMemsetAsync(deg, 0, (size_t)N * 4, stream);
    fused_init_k<<<fblocks, 256, 0, stream>>>(x, encW, encb, encls, enclb, h, N,
                                              edst, deg, E, Wl, Wr, Wp,
                                              cW1, cW1p, cW2, cW2p, cW3, cW3p,
                                              chW1, chW1p, chW2, chW2p, chW3, chW3p,
                                              tW1, tW1p, tW2, tW2p, dW1, dW1p);
    scan_k<<<1, 1024, 0, stream>>>(deg, row_ptr, fill, N);
    scatter_gemm0_k<<<sblocks, 256, 0, stream>>>(esrc, edst, fill, col, E, N, h,
                                                 Wp + 0, Wp + (size_t)65536,
                                                 bl + 0, br + 0, xlA, xrA);
    sortcol_k<<<nblk4, 256, 0, stream>>>(row_ptr, col, N);
    for (int l = 0; l < NL - 1; l++) {
        const unsigned short* xin_l = (l & 1) ? xlB : xlA;
        const unsigned short* xin_r = (l & 1) ? xrB : xrA;
        unsigned short* xout_l = (l & 1) ? xlA : xlB;
        unsigned short* xout_r = (l & 1) ? xrA : xrB;
        attn_k<<<nblk4, 256, 0, stream>>>(xin_l, xin_r, row_ptr, col, att + l * NH * NC,
                                          gb + l * D, gls + l * D, glb + l * D, h, l, N);
        gemm_lr_k<<<ntiles16, 256, 0, stream>>>(h,
                                                Wp + (size_t)((l + 1) * 2 + 0) * 65536,
                                                Wp + (size_t)((l + 1) * 2 + 1) * 65536,
                                                bl + (l + 1) * D, br + (l + 1) * D, xout_l, xout_r, N);
    }
    float* out = (float*)d_out;
    attn_k<<<nblk4, 256, 0, stream>>>(xlB, xrB, row_ptr, col, att + (NL - 1) * NH * NC,
                                      gb + (NL - 1) * D, gls + (NL - 1) * D, glb + (NL - 1) * D,
                                      h, NL - 1, N);
    colorhead_k<<<ntiles16, 1024, 0, stream>>>(h, N, cW1p, cb1, cW2p, cb2, cW3p, cb3, out);
    pool_k<<<dim3(BG, PS), 256, 0, stream>>>(h, batch, psum, pmax, cnt, N);
    gheads_k<<<3, 1024, 0, stream>>>(psum, pmax, cnt,
                                     chW1p, chb1, chW2p, chb2, chW3p, chb3,
                                     tW1p, tb1, tW2p, tb2, dW1p, db1, dW2, db2,
                                     out + (size_t)N * MC,
                                     out + (size_t)N * MC + BG * MC,
                                     out + (size_t)N * MC + BG * MC + BG * NT);
}

// Round 13
// 402.956 us; speedup vs baseline: 2.1414x; 1.0011x over previous
//
#include <hip/hip_runtime.h>
#include <hip/hip_bf16.h>

constexpr int DIN = 16;
constexpr int D   = 256;
constexpr int NH  = 8;
constexpr int NC  = 32;
constexpr int MC  = 200;
constexpr int NT  = 8;
constexpr int BG  = 16;
constexpr int NL  = 6;
constexpr int PS  = 16;   // pool slices per graph
constexpr float NEG = 0.2f;

typedef __attribute__((ext_vector_type(8))) short bfrag;
typedef __attribute__((ext_vector_type(4))) float f32x4;

__device__ inline unsigned short f2bf(float f) {
    unsigned int u = __float_as_uint(f);
    u += 0x7FFFu + ((u >> 16) & 1u);
    return (unsigned short)(u >> 16);
}
__device__ inline float bf2f(unsigned short u) {
    return __uint_as_float((unsigned int)u << 16);
}

// ---------------- device helpers ----------------

__device__ inline void enc_node(const float* x, const float* W, const float* b, const float* ls,
                                const float* lb, float* h, int n, int lane) {
    int c4 = lane * 4;
    float xs[DIN];
#pragma unroll
    for (int k = 0; k < DIN; k += 4) {
        float4 xv = *(const float4*)&x[n * DIN + k];
        xs[k] = xv.x; xs[k + 1] = xv.y; xs[k + 2] = xv.z; xs[k + 3] = xv.w;
    }
    float4 a = *(const float4*)&b[c4];
#pragma unroll
    for (int k = 0; k < DIN; k++) {
        float4 wv = *(const float4*)&W[k * D + c4];
        a.x = fmaf(xs[k], wv.x, a.x);
        a.y = fmaf(xs[k], wv.y, a.y);
        a.z = fmaf(xs[k], wv.z, a.z);
        a.w = fmaf(xs[k], wv.w, a.w);
    }
    float s = a.x + a.y + a.z + a.w;
#pragma unroll
    for (int msk = 1; msk <= 32; msk <<= 1) s += __shfl_xor(s, msk);
    float mu = s * (1.f / D);
    float4 dv = make_float4(a.x - mu, a.y - mu, a.z - mu, a.w - mu);
    float v2 = dv.x * dv.x + dv.y * dv.y + dv.z * dv.z + dv.w * dv.w;
#pragma unroll
    for (int msk = 1; msk <= 32; msk <<= 1) v2 += __shfl_xor(v2, msk);
    float rstd = rsqrtf(v2 * (1.f / D) + 1e-5f);
    float4 lsv = *(const float4*)&ls[c4];
    float4 lbv = *(const float4*)&lb[c4];
    float4 y = make_float4(fmaxf(dv.x * rstd * lsv.x + lbv.x, 0.f),
                           fmaxf(dv.y * rstd * lsv.y + lbv.y, 0.f),
                           fmaxf(dv.z * rstd * lsv.z + lbv.z, 0.f),
                           fmaxf(dv.w * rstd * lsv.w + lbv.w, 0.f));
    *(float4*)&h[(size_t)n * D + c4] = y;
}

// attn for one node (one full wave); depth-4 software pipeline.
// No running-max: logits bounded << exp overflow (order-free sums) —
// which also legalizes sorted-column processing.
__device__ inline float4 attn_compute(const unsigned short* xl, const unsigned short* xr,
                                      int beg, int deg, int myc, const int* col,
                                      const float* att,
                                      const float* gb, const float* gls, const float* glb,
                                      const float* h, int layer, int n, int lane) {
    int c4 = lane * 4;
    ushort4 xr4 = *(const ushort4*)&xr[(size_t)n * D + c4];
    float4 xrv = make_float4(bf2f(xr4.x), bf2f(xr4.y), bf2f(xr4.z), bf2f(xr4.w));
    float4 av  = *(const float4*)&att[c4];
    float l = 0.f;
    float4 acc = make_float4(0.f, 0.f, 0.f, 0.f);
    auto loadx = [&](int i) -> ushort4 {
        if (i < deg) {
            int s = (i < 64) ? __shfl(myc, i) : col[beg + i];
            return *(const ushort4*)&xl[(size_t)s * D + c4];
        }
        return make_ushort4(0, 0, 0, 0);
    };
    auto step = [&](ushort4 x4) {
        float4 xlv = make_float4(bf2f(x4.x), bf2f(x4.y), bf2f(x4.z), bf2f(x4.w));
        float sx = xlv.x + xrv.x; sx = sx > 0.f ? sx : NEG * sx;
        float sy = xlv.y + xrv.y; sy = sy > 0.f ? sy : NEG * sy;
        float sz = xlv.z + xrv.z; sz = sz > 0.f ? sz : NEG * sz;
        float sw = xlv.w + xrv.w; sw = sw > 0.f ? sw : NEG * sw;
        float z = av.x * sx + av.y * sy + av.z * sz + av.w * sw;
        z += __shfl_xor(z, 1); z += __shfl_xor(z, 2); z += __shfl_xor(z, 4);
        float p = __expf(z);
        l += p;
        acc.x = fmaf(p, xlv.x, acc.x);
        acc.y = fmaf(p, xlv.y, acc.y);
        acc.z = fmaf(p, xlv.z, acc.z);
        acc.w = fmaf(p, xlv.w, acc.w);
    };
    ushort4 b0 = loadx(0), b1 = loadx(1), b2 = loadx(2), b3 = loadx(3);
    int e = 0;
    for (; e + 4 <= deg; e += 4) {
        ushort4 n0 = loadx(e + 4), n1 = loadx(e + 5), n2 = loadx(e + 6), n3 = loadx(e + 7);
        step(b0); step(b1); step(b2); step(b3);
        b0 = n0; b1 = n1; b2 = n2; b3 = n3;
    }
    if (e + 0 < deg) step(b0);
    if (e + 1 < deg) step(b1);
    if (e + 2 < deg) step(b2);
    float4 gbv = *(const float4*)&gb[c4];
    float rl = 1.f / l;
    float4 o = make_float4(acc.x * rl + gbv.x, acc.y * rl + gbv.y,
                           acc.z * rl + gbv.z, acc.w * rl + gbv.w);
    float s = o.x + o.y + o.z + o.w;
#pragma unroll
    for (int msk = 1; msk <= 32; msk <<= 1) s += __shfl_xor(s, msk);
    float mu = s * (1.f / D);
    float4 dv = make_float4(o.x - mu, o.y - mu, o.z - mu, o.w - mu);
    float v2 = dv.x * dv.x + dv.y * dv.y + dv.z * dv.z + dv.w * dv.w;
#pragma unroll
    for (int msk = 1; msk <= 32; msk <<= 1) v2 += __shfl_xor(v2, msk);
    float rstd = rsqrtf(v2 * (1.f / D) + 1e-5f);
    float4 glsv = *(const float4*)&gls[c4];
    float4 glbv = *(const float4*)&glb[c4];
    float y0 = dv.x * rstd * glsv.x + glbv.x;
    float y1 = dv.y * rstd * glsv.y + glbv.y;
    float y2 = dv.z * rstd * glsv.z + glbv.z;
    float y3 = dv.w * rstd * glsv.w + glbv.w;
    y0 = y0 > 0.f ? y0 : expm1f(y0);
    y1 = y1 > 0.f ? y1 : expm1f(y1);
    y2 = y2 > 0.f ? y2 : expm1f(y2);
    y3 = y3 > 0.f ? y3 : expm1f(y3);
    float4 prev = make_float4(0.f, 0.f, 0.f, 0.f);
    if (layer > 0) prev = *(const float4*)&h[(size_t)n * D + c4];
    return make_float4(prev.x + y0, prev.y + y1, prev.z + y2, prev.w + y3);
}

// MFMA GEMM on a 16-row tile, one wave handles one 16-col tile (ctg).
__device__ inline void gemm_one_ct(const unsigned short (*As)[264],
                                   const unsigned short* WpL, const unsigned short* WpR,
                                   const float* bl, const float* br,
                                   unsigned short* xl, unsigned short* xr,
                                   int N, int nb, int ctg, int lane) {
    int m = lane & 15, q = lane >> 4;
    float bLv = bl[ctg * 16 + m];
    float bRv = br[ctg * 16 + m];
    f32x4 accL = (f32x4){bLv, bLv, bLv, bLv};
    f32x4 accR = (f32x4){bRv, bRv, bRv, bRv};
#pragma unroll
    for (int ks = 0; ks < 8; ks++) {
        bfrag af = *(const bfrag*)&As[m][ks * 32 + q * 8];
        size_t off = (((size_t)ctg * 8 + ks) * 64 + lane) * 8;
        bfrag bL = *(const bfrag*)&WpL[off];
        bfrag bR = *(const bfrag*)&WpR[off];
        accL = __builtin_amdgcn_mfma_f32_16x16x32_bf16(af, bL, accL, 0, 0, 0);
        accR = __builtin_amdgcn_mfma_f32_16x16x32_bf16(af, bR, accR, 0, 0, 0);
    }
    int colg = ctg * 16 + m;
#pragma unroll
    for (int reg = 0; reg < 4; reg++) {
        int row = nb + q * 4 + reg;
        if (row < N) {
            xl[(size_t)row * D + colg] = f2bf(accL[reg]);
            xr[(size_t)row * D + colg] = f2bf(accR[reg]);
        }
    }
}

// 4-wave variant (wave w owns col-tiles w*4..w*4+3)
__device__ inline void gemm_core(const unsigned short (*As)[264],
                                 const unsigned short* WpL, const unsigned short* WpR,
                                 const float* bl, const float* br,
                                 unsigned short* xl, unsigned short* xr, int N, int nb, int T) {
    int lane = T & 63, w = T >> 6;
#pragma unroll
    for (int ct = 0; ct < 4; ct++)
        gemm_one_ct(As, WpL, WpR, bl, br, xl, xr, N, nb, w * 4 + ct, lane);
}

// generic 16-row MFMA tile for the graph heads: A is bf16 [16][LDA] in LDS,
// Wp packed by repack_gen layout, K = NKS*32 unrolled at compile time.
template<int NKS>
__device__ inline f32x4 head_mma(const unsigned short* A, int LDA,
                                 const unsigned short* Wp, int ct,
                                 const float* bias, int NCOL, int lane) {
    int m = lane & 15;
    int colg = ct * 16 + m;
    float bv = (colg < NCOL) ? bias[colg] : 0.f;
    f32x4 acc = (f32x4){bv, bv, bv, bv};
#pragma unroll
    for (int ks = 0; ks < NKS; ks++) {
        bfrag af = *(const bfrag*)&A[m * LDA + ks * 32 + (lane >> 4) * 8];
        bfrag bf = *(const bfrag*)&Wp[(((size_t)ct * NKS + ks) * 64 + lane) * 8];
        acc = __builtin_amdgcn_mfma_f32_16x16x32_bf16(af, bf, acc, 0, 0, 0);
    }
    return acc;   // row = (lane>>4)*4 + reg, col = ct*16 + (lane&15)
}

__device__ inline void repack_attn_one(const float* Wl, const float* Wr, unsigned short* Wp, int tid) {
    int lane = tid & 63;
    int r1 = tid >> 6;
    int ks = r1 & 7;
    int r2 = r1 >> 3;
    int ct = r2 & 15;
    int mi = r2 >> 4;
    int layer = mi >> 1, mat = mi & 1;
    const float* W = (mat == 0 ? Wl : Wr) + (size_t)layer * D * D;
    int n = ct * 16 + (lane & 15);
    int kb = ks * 32 + (lane >> 4) * 8;
    size_t base = (((size_t)(mi * 16 + ct) * 8 + ks) * 64 + lane) * 8;
#pragma unroll
    for (int j = 0; j < 8; j++) Wp[base + j] = f2bf(W[(size_t)(kb + j) * D + n]);
}

__device__ inline void repack_gen_one(const float* W, unsigned short* Wp, int K, int NCOL, int nks, int tid) {
    int lane = tid & 63;
    int r = tid >> 6;
    int ks = r % nks;
    int ct = r / nks;
    int n = ct * 16 + (lane & 15);
    int kb = ks * 32 + (lane >> 4) * 8;
    size_t base = (((size_t)ct * nks + ks) * 64 + lane) * 8;
#pragma unroll
    for (int j = 0; j < 8; j++) {
        int k = kb + j;
        Wp[base + j] = (n < NCOL && k < K) ? f2bf(W[(size_t)k * NCOL + n]) : (unsigned short)0;
    }
}

// ---------------- kernels ----------------

// encoder + edge count + all weight repacks (incl. graph-head weights), fused.
__global__ __launch_bounds__(256) void fused_init_k(const float* __restrict__ x, const float* __restrict__ encW,
                                                    const float* __restrict__ encb, const float* __restrict__ encls,
                                                    const float* __restrict__ enclb, float* __restrict__ h, int N,
                                                    const int* __restrict__ dst, int* __restrict__ deg, int E,
                                                    const float* __restrict__ Wl, const float* __restrict__ Wr,
                                                    unsigned short* __restrict__ Wp,
                                                    const float* __restrict__ cW1, unsigned short* __restrict__ cW1p,
                                                    const float* __restrict__ cW2, unsigned short* __restrict__ cW2p,
                                                    const float* __restrict__ cW3, unsigned short* __restrict__ cW3p,
                                                    const float* __restrict__ chW1, unsigned short* __restrict__ chW1p,
                                                    const float* __restrict__ chW2, unsigned short* __restrict__ chW2p,
                                                    const float* __restrict__ chW3, unsigned short* __restrict__ chW3p,
                                                    const float* __restrict__ tW1, unsigned short* __restrict__ tW1p,
                                                    const float* __restrict__ tW2, unsigned short* __restrict__ tW2p,
                                                    const float* __restrict__ dW1, unsigned short* __restrict__ dW1p) {
    int gid = blockIdx.x * 256 + threadIdx.x;
    int lane = threadIdx.x & 63;
    int n = blockIdx.x * 4 + (threadIdx.x >> 6);
    if (n < N) enc_node(x, encW, encb, encls, enclb, h, n, lane);
    if (gid < E) atomicAdd(&deg[dst[gid]], 1);
    if (gid < NL * 2 * 16 * 8 * 64) repack_attn_one(Wl, Wr, Wp, gid);
    if (gid < 16 * 8 * 64) repack_gen_one(cW1, cW1p, D, D, 8, gid);
    if (gid < 8 * 8 * 64)  repack_gen_one(cW2, cW2p, D, 128, 8, gid);
    if (gid < 13 * 4 * 64) repack_gen_one(cW3, cW3p, 128, MC, 4, gid);
    // graph-head packs on disjoint gid ranges (spread across later blocks)
    int g2 = gid - NL * 2 * 16 * 8 * 64;
    if (g2 >= 0 && g2 < 16 * 16 * 64) repack_gen_one(chW1, chW1p, 2 * D, D, 16, g2);
    g2 -= 16 * 16 * 64;
    if (g2 >= 0 && g2 < 8 * 8 * 64)   repack_gen_one(chW2, chW2p, D, 128, 8, g2);
    g2 -= 8 * 8 * 64;
    if (g2 >= 0 && g2 < 13 * 4 * 64)  repack_gen_one(chW3, chW3p, 128, MC, 4, g2);
    g2 -= 13 * 4 * 64;
    if (g2 >= 0 && g2 < 8 * 16 * 64)  repack_gen_one(tW1, tW1p, 2 * D, 128, 16, g2);
    g2 -= 8 * 16 * 64;
    if (g2 >= 0 && g2 < 1 * 4 * 64)   repack_gen_one(tW2, tW2p, 128, NT, 4, g2);
    g2 -= 1 * 4 * 64;
    if (g2 >= 0 && g2 < 4 * 16 * 64)  repack_gen_one(dW1, dW1p, 2 * D, 64, 16, g2);
}

// single-block scan. deg holds in-degree only; +1 accounts for the self loop.
__global__ __launch_bounds__(1024) void scan_k(const int* __restrict__ deg, int* __restrict__ row_ptr,
                                               int* __restrict__ fill, int N) {
    __shared__ int sd[1024];
    int t = threadIdx.x;
    int chunk = (N + 1023) >> 10;
    int lo = t * chunk, hi = min(lo + chunk, N);
    int s = 0;
    for (int i = lo; i < hi; i++) s += deg[i] + 1;
    sd[t] = s;
    __syncthreads();
    for (int off = 1; off < 1024; off <<= 1) {
        int v = (t >= off) ? sd[t - off] : 0;
        __syncthreads();
        sd[t] += v;
        __syncthreads();
    }
    int run = (t > 0) ? sd[t - 1] : 0;
    for (int i = lo; i < hi; i++) {
        row_ptr[i] = run; fill[i] = run;
        run += deg[i] + 1;
    }
    if (t == 1023) row_ptr[N] = sd[1023];
}

// scatter + layer-0 GEMM
__global__ __launch_bounds__(256) void scatter_gemm0_k(const int* __restrict__ src, const int* __restrict__ dst,
                                                       int* __restrict__ fill, int* __restrict__ col, int E, int N,
                                                       const float* __restrict__ h,
                                                       const unsigned short* __restrict__ WpL,
                                                       const unsigned short* __restrict__ WpR,
                                                       const float* __restrict__ bl, const float* __restrict__ br,
                                                       unsigned short* __restrict__ xl, unsigned short* __restrict__ xr) {
    __shared__ unsigned short As[16][264];
    int T = threadIdx.x;
    int tt = blockIdx.x;
    int ntiles = (N + 15) >> 4;
    if (tt < ntiles) {
        int nb = tt * 16;
#pragma unroll
        for (int r = 0; r < 16; r++) {
            int row = nb + r;
            float v = (row < N) ? h[(size_t)row * D + T] : 0.f;
            As[r][T] = f2bf(v);
        }
        __syncthreads();
        gemm_core(As, WpL, WpR, bl, br, xl, xr, N, nb, T);
    }
    for (int e = blockIdx.x * 256 + T; e < E + N; e += gridDim.x * 256) {
        if (e < E) {
            int p = atomicAdd(&fill[dst[e]], 1);
            col[p] = src[e];
        } else {
            int n = e - E;
            int p = atomicAdd(&fill[n], 1);
            col[p] = n;
        }
    }
}

// attention-only kernel: 256 threads = 4 waves, ONE node per wave, no LDS, no barriers.
// __launch_bounds__(256, 8): VGPR cap 64 (kernel needs ~44-48, no spill) =>
// 8 blocks/CU = 32 waves/CU resident — doubles the TLP hiding the ~270cyc/step
// gather stall (R9 counters: 30% occupancy, 43% VALUBusy at 4 blocks/CU).
// Layer 0 additionally sorts its own row in-register (bitonic) and writes it
// back — replaces the separate sortcol dispatch (legal: order-free sums).
__global__ __launch_bounds__(256, 8) void attn_k(const unsigned short* __restrict__ xl_in,
                                                 const unsigned short* __restrict__ xr_in,
                                                 const int* __restrict__ row_ptr, int* __restrict__ col,
                                                 const float* __restrict__ att, const float* __restrict__ gb,
                                                 const float* __restrict__ gls, const float* __restrict__ glb,
                                                 float* __restrict__ h, int layer, int N) {
    int T = threadIdx.x;
    int lane = T & 63, wv = T >> 6;
    int n = blockIdx.x * 4 + wv;
    if (n >= N) return;
    int beg = row_ptr[n], deg = row_ptr[n + 1] - beg;
    int myc = col[beg + min(lane, deg - 1)];
    if (layer == 0 && deg <= 64) {
        int key = (lane < deg) ? myc : 0x7FFFFFFF;
#pragma unroll
        for (int k = 2; k <= 64; k <<= 1) {
#pragma unroll
            for (int j = k >> 1; j > 0; j >>= 1) {
                int other = __shfl_xor(key, j);
                bool up = ((lane & k) == 0);
                key = ((((lane & j) == 0) == up) ? min(key, other) : max(key, other));
            }
        }
        if (lane < deg) col[beg + lane] = key;
        myc = key;
    }
    float4 res = attn_compute(xl_in, xr_in, beg, deg, myc, col, att, gb, gls, glb,
                              h, layer, n, lane);
    *(float4*)&h[(size_t)n * D + lane * 4] = res;
}

// GEMM-only kernel: reads h (f32), produces xl/xr (bf16) for the NEXT layer.
__global__ __launch_bounds__(256, 4) void gemm_lr_k(const float* __restrict__ h,
                                                    const unsigned short* __restrict__ WpL,
                                                    const unsigned short* __restrict__ WpR,
                                                    const float* __restrict__ bl, const float* __restrict__ br,
                                                    unsigned short* __restrict__ xl, unsigned short* __restrict__ xr,
                                                    int N) {
    __shared__ unsigned short As[16][264];
    int T = threadIdx.x;
    int nb = blockIdx.x * 16;
#pragma unroll
    for (int r = 0; r < 16; r++) {
        int row = nb + r;
        float v = (row < N) ? h[(size_t)row * D + T] : 0.f;
        As[r][T] = f2bf(v);
    }
    __syncthreads();
    gemm_core(As, WpL, WpR, bl, br, xl, xr, N, nb, T);
}

// color-head MLP (MFMA), reads h: 1024 threads, 16 nodes/block.
__global__ __launch_bounds__(1024) void colorhead_k(const float* __restrict__ h, int N,
                                                    const unsigned short* __restrict__ W1p, const float* __restrict__ b1,
                                                    const unsigned short* __restrict__ W2p, const float* __restrict__ b2,
                                                    const unsigned short* __restrict__ W3p, const float* __restrict__ b3,
                                                    float* __restrict__ out) {
    __shared__ unsigned short As[16][264];
    __shared__ unsigned short Zs[16][264];
    int T = threadIdx.x;
    int lane = T & 63, wv = T >> 6;
    int nb = blockIdx.x * 16;
    int c4 = lane * 4;
    int n = nb + wv;
    if (n < N) {
        float4 v = *(const float4*)&h[(size_t)n * D + c4];
        As[wv][c4 + 0] = f2bf(v.x);
        As[wv][c4 + 1] = f2bf(v.y);
        As[wv][c4 + 2] = f2bf(v.z);
        As[wv][c4 + 3] = f2bf(v.w);
    } else {
        As[wv][c4 + 0] = 0; As[wv][c4 + 1] = 0; As[wv][c4 + 2] = 0; As[wv][c4 + 3] = 0;
    }
    __syncthreads();
    int m = lane & 15, q = lane >> 4;
    {
        float bv = b1[wv * 16 + m];
        f32x4 acc = (f32x4){bv, bv, bv, bv};
#pragma unroll
        for (int ks = 0; ks < 8; ks++) {
            bfrag af = *(const bfrag*)&As[m][ks * 32 + q * 8];
            bfrag bf = *(const bfrag*)&W1p[(((size_t)wv * 8 + ks) * 64 + lane) * 8];
            acc = __builtin_amdgcn_mfma_f32_16x16x32_bf16(af, bf, acc, 0, 0, 0);
        }
        int colg = wv * 16 + m;
#pragma unroll
        for (int reg = 0; reg < 4; reg++)
            Zs[q * 4 + reg][colg] = f2bf(fmaxf(acc[reg], 0.f));
    }
    __syncthreads();
    if (wv < 8) {
        float bv = b2[wv * 16 + m];
        f32x4 acc = (f32x4){bv, bv, bv, bv};
#pragma unroll
        for (int ks = 0; ks < 8; ks++) {
            bfrag af = *(const bfrag*)&Zs[m][ks * 32 + q * 8];
            bfrag bf = *(const bfrag*)&W2p[(((size_t)wv * 8 + ks) * 64 + lane) * 8];
            acc = __builtin_amdgcn_mfma_f32_16x16x32_bf16(af, bf, acc, 0, 0, 0);
        }
        int colg = wv * 16 + m;
#pragma unroll
        for (int reg = 0; reg < 4; reg++)
            As[q * 4 + reg][colg] = f2bf(fmaxf(acc[reg], 0.f));
    }
    __syncthreads();
    if (wv < 13) {
        int colg = wv * 16 + m;
        float bv = (colg < MC) ? b3[colg] : 0.f;
        f32x4 acc = (f32x4){bv, bv, bv, bv};
#pragma unroll
        for (int ks = 0; ks < 4; ks++) {
            bfrag af = *(const bfrag*)&As[m][ks * 32 + q * 8];
            bfrag bf = *(const bfrag*)&W3p[(((size_t)wv * 4 + ks) * 64 + lane) * 8];
            acc = __builtin_amdgcn_mfma_f32_16x16x32_bf16(af, bf, acc, 0, 0, 0);
        }
#pragma unroll
        for (int reg = 0; reg < 4; reg++) {
            int row = nb + q * 4 + reg;
            if (row < N && colg < MC) out[(size_t)row * MC + colg] = acc[reg];
        }
    }
}

// pooling stage 1 (256 blocks: 16 graphs x 16 slices); 4-way unrolled column walk
__global__ __launch_bounds__(256) void pool_k(const float* __restrict__ h, const int* __restrict__ batch,
                                              float* __restrict__ psum, float* __restrict__ pmax,
                                              int* __restrict__ cnt, int N) {
    int b = blockIdx.x;
    int sl = blockIdx.y;
    int c = threadIdx.x;
    int lo = 0, hi = N;
    while (lo < hi) { int mid = (lo + hi) >> 1; if (batch[mid] < b) lo = mid + 1; else hi = mid; }
    int s0 = lo;
    lo = 0; hi = N;
    while (lo < hi) { int mid = (lo + hi) >> 1; if (batch[mid] < b + 1) lo = mid + 1; else hi = mid; }
    int s1 = lo;
    int len = s1 - s0;
    int chunk = (len + PS - 1) / PS;
    int n0 = s0 + sl * chunk;
    int n1 = min(n0 + chunk, s1);
    float a0 = 0.f, a1 = 0.f, a2 = 0.f, a3 = 0.f;
    float m0 = -3.0e38f, m1 = -3.0e38f, m2 = -3.0e38f, m3 = -3.0e38f;
    int n = n0;
    for (; n + 4 <= n1; n += 4) {
        float v0 = h[(size_t)(n + 0) * D + c];
        float v1 = h[(size_t)(n + 1) * D + c];
        float v2 = h[(size_t)(n + 2) * D + c];
        float v3 = h[(size_t)(n + 3) * D + c];
        a0 += v0; a1 += v1; a2 += v2; a3 += v3;
        m0 = fmaxf(m0, v0); m1 = fmaxf(m1, v1);
        m2 = fmaxf(m2, v2); m3 = fmaxf(m3, v3);
    }
    for (; n < n1; n++) {
        float v = h[(size_t)n * D + c];
        a0 += v; m0 = fmaxf(m0, v);
    }
    float sum = (a0 + a1) + (a2 + a3);
    float mx = fmaxf(fmaxf(m0, m1), fmaxf(m2, m3));
    psum[(size_t)(b * PS + sl) * D + c] = sum;
    pmax[(size_t)(b * PS + sl) * D + c] = mx;
    if (c == 0 && sl == 0) cnt[b] = len;
}

// graph heads via MFMA: 3 blocks (chromatic / type / difficulty), 1024 threads each.
__global__ __launch_bounds__(1024) void gheads_k(const float* __restrict__ psum, const float* __restrict__ pmax,
                                                 const int* __restrict__ cnt,
                                                 const unsigned short* __restrict__ chW1p, const float* __restrict__ chb1,
                                                 const unsigned short* __restrict__ chW2p, const float* __restrict__ chb2,
                                                 const unsigned short* __restrict__ chW3p, const float* __restrict__ chb3,
                                                 const unsigned short* __restrict__ tW1p, const float* __restrict__ tb1,
                                                 const unsigned short* __restrict__ tW2p, const float* __restrict__ tb2,
                                                 const unsigned short* __restrict__ dW1p, const float* __restrict__ db1,
                                                 const float* __restrict__ dW2, const float* __restrict__ db2,
                                                 float* __restrict__ out_ch, float* __restrict__ out_t,
                                                 float* __restrict__ out_d) {
    __shared__ unsigned short Gs[16][520];   // g = [mean || max], bf16
    __shared__ unsigned short Z1[16][264];
    __shared__ unsigned short Z2[16][136];
    __shared__ float Zd[16][68];
    int T = threadIdx.x;
    int sec = blockIdx.x;
    // assemble g (16 graphs x 512)
    for (int i = T; i < 16 * 512; i += 1024) {
        int b = i >> 9, c = i & 511;
        bool isMean = c < 256;
        int ch = c & 255;
        float acc = isMean ? 0.f : -3.0e38f;
#pragma unroll
        for (int sl = 0; sl < PS; sl++) {
            float v = isMean ? psum[(size_t)(b * PS + sl) * D + ch]
                             : pmax[(size_t)(b * PS + sl) * D + ch];
            acc = isMean ? (acc + v) : fmaxf(acc, v);
        }
        int cn = cnt[b];
        float v = isMean ? (acc / fmaxf((float)cn, 1.f)) : ((cn > 0) ? acc : 0.f);
        Gs[b][c] = f2bf(v);
    }
    __syncthreads();
    int lane = T & 63, wv = T >> 6;
    int m = lane & 15, q = lane >> 4;
    if (sec == 0) {
        {
            f32x4 acc = head_mma<16>(&Gs[0][0], 520, chW1p, wv, chb1, 256, lane);
            int colg = wv * 16 + m;
#pragma unroll
            for (int r = 0; r < 4; r++)
                Z1[q * 4 + r][colg] = f2bf(fmaxf(acc[r], 0.f));
        }
        __syncthreads();
        if (wv < 8) {
            f32x4 acc = head_mma<8>(&Z1[0][0], 264, chW2p, wv, chb2, 128, lane);
            int colg = wv * 16 + m;
#pragma unroll
            for (int r = 0; r < 4; r++)
                Z2[q * 4 + r][colg] = f2bf(fmaxf(acc[r], 0.f));
        }
        __syncthreads();
        if (wv < 13) {
            f32x4 acc = head_mma<4>(&Z2[0][0], 136, chW3p, wv, chb3, MC, lane);
            int colg = wv * 16 + m;
#pragma unroll
            for (int r = 0; r < 4; r++)
                if (colg < MC) out_ch[(q * 4 + r) * MC + colg] = acc[r];
        }
    } else if (sec == 1) {
        if (wv < 8) {
            f32x4 acc = head_mma<16>(&Gs[0][0], 520, tW1p, wv, tb1, 128, lane);
            int colg = wv * 16 + m;
#pragma unroll
            for (int r = 0; r < 4; r++)
                Z1[q * 4 + r][colg] = f2bf(fmaxf(acc[r], 0.f));
        }
        __syncthreads();
        if (wv == 0) {
            f32x4 acc = head_mma<4>(&Z1[0][0], 264, tW2p, 0, tb2, NT, lane);
#pragma unroll
            for (int r = 0; r < 4; r++)
                if (m < NT) out_t[(q * 4 + r) * NT + m] = acc[r];
        }
    } else {
        if (wv < 4) {
            f32x4 acc = head_mma<16>(&Gs[0][0], 520, dW1p, wv, db1, 64, lane);
            int colg = wv * 16 + m;
#pragma unroll
            for (int r = 0; r < 4; r++)
                Zd[q * 4 + r][colg] = fmaxf(acc[r], 0.f);
        }
        __syncthreads();
        if (wv == 0) {
            int g = lane >> 2, j0 = lane & 3;
            float s = 0.f;
#pragma unroll
            for (int j = 0; j < 16; j++) s = fmaf(Zd[g][j0 + 4 * j], dW2[j0 + 4 * j], s);
            s += __shfl_xor(s, 1);
            s += __shfl_xor(s, 2);
            if (j0 == 0) {
                float a = db2[0] + s;
                out_d[g] = 100.f / (1.f + __expf(-a));
            }
        }
    }
}

// ----------------------------------------------------------------
extern "C" void kernel_launch(void* const* d_in, const int* in_sizes, int n_in,
                              void* d_out, int out_size, void* d_ws, size_t ws_size,
                              hipStream_t stream) {
    const float* x     = (const float*)d_in[0];
    const int*   ei    = (const int*)d_in[1];
    const int*   batch = (const int*)d_in[2];
    const float* encW  = (const float*)d_in[3];
    const float* encb  = (const float*)d_in[4];
    const float* encls = (const float*)d_in[5];
    const float* enclb = (const float*)d_in[6];
    const float* Wl    = (const float*)d_in[7];
    const float* bl    = (const float*)d_in[8];
    const float* Wr    = (const float*)d_in[9];
    const float* br    = (const float*)d_in[10];
    const float* att   = (const float*)d_in[11];
    const float* gb    = (const float*)d_in[12];
    const float* gls   = (const float*)d_in[13];
    const float* glb   = (const float*)d_in[14];
    const float* cW1   = (const float*)d_in[15];
    const float* cb1   = (const float*)d_in[16];
    const float* cW2   = (const float*)d_in[17];
    const float* cb2   = (const float*)d_in[18];
    const float* cW3   = (const float*)d_in[19];
    const float* cb3   = (const float*)d_in[20];
    const float* chW1  = (const float*)d_in[21];
    const float* chb1  = (const float*)d_in[22];
    const float* chW2  = (const float*)d_in[23];
    const float* chb2  = (const float*)d_in[24];
    const float* chW3  = (const float*)d_in[25];
    const float* chb3  = (const float*)d_in[26];
    const float* tW1   = (const float*)d_in[27];
    const float* tb1   = (const float*)d_in[28];
    const float* tW2   = (const float*)d_in[29];
    const float* tb2   = (const float*)d_in[30];
    const float* dW1   = (const float*)d_in[31];
    const float* db1   = (const float*)d_in[32];
    const float* dW2   = (const float*)d_in[33];
    const float* db2   = (const float*)d_in[34];

    const int N = in_sizes[0] / DIN;
    const int E = in_sizes[1] / 2;
    const int* esrc = ei;
    const int* edst = ei + E;

    char* p = (char*)d_ws;
    auto carve = [&](size_t bytes) { char* r = p; p += (bytes + 255) & ~(size_t)255; return r; };
    int*            row_ptr = (int*)carve((size_t)(N + 1) * 4);
    int*            fill    = (int*)carve((size_t)N * 4);
    int*            deg     = (int*)carve((size_t)N * 4);
    int*            cnt     = (int*)carve((size_t)BG * 4);
    float*          psum    = (float*)carve((size_t)BG * PS * D * 4);
    float*          pmax    = (float*)carve((size_t)BG * PS * D * 4);
    int*            col     = (int*)carve((size_t)(E + N) * 4);
    unsigned short* Wp      = (unsigned short*)carve((size_t)NL * 2 * 65536 * 2);
    unsigned short* cW1p    = (unsigned short*)carve((size_t)16 * 8 * 64 * 8 * 2);
    unsigned short* cW2p    = (unsigned short*)carve((size_t)8 * 8 * 64 * 8 * 2);
    unsigned short* cW3p    = (unsigned short*)carve((size_t)13 * 4 * 64 * 8 * 2);
    unsigned short* chW1p   = (unsigned short*)carve((size_t)16 * 16 * 64 * 8 * 2);
    unsigned short* chW2p   = (unsigned short*)carve((size_t)8 * 8 * 64 * 8 * 2);
    unsigned short* chW3p   = (unsigned short*)carve((size_t)13 * 4 * 64 * 8 * 2);
    unsigned short* tW1p    = (unsigned short*)carve((size_t)8 * 16 * 64 * 8 * 2);
    unsigned short* tW2p    = (unsigned short*)carve((size_t)1 * 4 * 64 * 8 * 2);
    unsigned short* dW1p    = (unsigned short*)carve((size_t)4 * 16 * 64 * 8 * 2);
    float*          h       = (float*)carve((size_t)N * D * 4);
    unsigned short* xlA     = (unsigned short*)carve((size_t)N * D * 2);
    unsigned short* xrA     = (unsigned short*)carve((size_t)N * D * 2);
    unsigned short* xlB     = (unsigned short*)carve((size_t)N * D * 2);
    unsigned short* xrB     = (unsigned short*)carve((size_t)N * D * 2);
    (void)ws_size; (void)n_in; (void)out_size;

    const int ntiles16 = (N + 15) / 16;
    const int nblk4    = (N + 3) / 4;
    const int sblocks  = max(ntiles16, (E + N + 255) / 256);
    const int fblocks  = max((N + 3) / 4, max((E + 255) / 256, 576));

    hipMemsetAsync(deg, 0, (size_t)N * 4, stream);
    fused_init_k<<<fblocks, 256, 0, stream>>>(x, encW, encb, encls, enclb, h, N,
                                              edst, deg, E, Wl, Wr, Wp,
                                              cW1, cW1p, cW2, cW2p, cW3, cW3p,
                                              chW1, chW1p, chW2, chW2p, chW3, chW3p,
                                              tW1, tW1p, tW2, tW2p, dW1, dW1p);
    scan_k<<<1, 1024, 0, stream>>>(deg, row_ptr, fill, N);
    scatter_gemm0_k<<<sblocks, 256, 0, stream>>>(esrc, edst, fill, col, E, N, h,
                                                 Wp + 0, Wp + (size_t)65536,
                                                 bl + 0, br + 0, xlA, xrA);
    for (int l = 0; l < NL - 1; l++) {
        const unsigned short* xin_l = (l & 1) ? xlB : xlA;
        const unsigned short* xin_r = (l & 1) ? xrB : xrA;
        unsigned short* xout_l = (l & 1) ? xlA : xlB;
        unsigned short* xout_r = (l & 1) ? xrA : xrB;
        attn_k<<<nblk4, 256, 0, stream>>>(xin_l, xin_r, row_ptr, col, att + l * NH * NC,
                                          gb + l * D, gls + l * D, glb + l * D, h, l, N);
        gemm_lr_k<<<ntiles16, 256, 0, stream>>>(h,
                                                Wp + (size_t)((l + 1) * 2 + 0) * 65536,
                                                Wp + (size_t)((l + 1) * 2 + 1) * 65536,
                                                bl + (l + 1) * D, br + (l + 1) * D, xout_l, xout_r, N);
    }
    float* out = (float*)d_out;
    attn_k<<<nblk4, 256, 0, stream>>>(xlB, xrB, row_ptr, col, att + (NL - 1) * NH * NC,
                                      gb + (NL - 1) * D, gls + (NL - 1) * D, glb + (NL - 1) * D,
                                      h, NL - 1, N);
    colorhead_k<<<ntiles16, 1024, 0, stream>>>(h, N, cW1p, cb1, cW2p, cb2, cW3p, cb3, out);
    pool_k<<<dim3(BG, PS), 256, 0, stream>>>(h, batch, psum, pmax, cnt, N);
    gheads_k<<<3, 1024, 0, stream>>>(psum, pmax, cnt,
                                     chW1p, chb1, chW2p, chb2, chW3p, chb3,
                                     tW1p, tb1, tW2p, tb2, dW1p, db1, dW2, db2,
                                     out + (size_t)N * MC,
                                     out + (size_t)N * MC + BG * MC,
                                     out + (size_t)N * MC + BG * MC + BG * NT);
}